// Round 1
// baseline (565.890 us; speedup 1.0000x reference)
//
#include <hip/hip_runtime.h>
#include <hip/hip_cooperative_groups.h>
#include <math.h>

namespace cg = cooperative_groups;

#define NL 512
#define NP 1024
#define HDIM 128

#define TAB_N 8192
#define DMAX 34.65f

// ---- workspace layout (float offsets) ----
#define M_OFF    128
#define WLT_OFF  (M_OFF)                      // WlT  [128][128]
#define WPT_OFF  (M_OFF + 16384)              // WpT  [128][128]
#define WQT_OFF  (M_OFF + 32768)              // WqkvT[128][384]
#define WOT_OFF  (M_OFF + 81920)              // WoT  [128][128]
#define WGLT_OFF (M_OFF + 98304)              // WglT [256][128]
#define WGPT_OFF (M_OFF + 131072)             // WgpT [256][128]
#define TAB_OFF  (M_OFF + 163840)             // m(d) table
#define LIG_OFF  (M_OFF + NL*NP)              // lig proj 512x128
#define POC_OFF  (LIG_OFF + NL*HDIM)          // poc proj 1024x128
#define LENH_OFF (POC_OFF + NP*HDIM)          // lig_enh 512x128
#define PENH_OFF (LENH_OFF + NL*HDIM)         // poc_enh 1024x128
#define QKVL_OFF (PENH_OFF + NP*HDIM)         // qkv for lig_enh 512x384
#define QKVP_OFF (QKVL_OFF + NL*384)          // qkv for poc_enh 1024x384
#define PARTL_OFF (QKVP_OFF + NP*384)         // lig partials: [512][8 h][8 slices][18]
#define PARTP_OFF (PARTL_OFF + 512*8*8*18)    // poc partials: [1024][8 h][4 slices][18]
#define AGG_OFF   (PARTP_OFF + 1024*8*4*18)   // agg result [1536][128]

__device__ __forceinline__ float dot4f(float4 a, float4 b){
  return fmaf(a.x,b.x, fmaf(a.y,b.y, fmaf(a.z,b.z, a.w*b.w)));
}

// =====================================================================================
// Fused cooperative kernel: 512 blocks x 512 threads, 64 KB LDS (2 blocks/CU resident).
// Phases: P0 transpose | P1 proj+LUT | P2a softmax+agg | P2b gate+QKV | P3 attn | P4 merge+LN
// =====================================================================================
__global__ __launch_bounds__(512, 4) void fused_all(
  const float* __restrict__ lf, const float* __restrict__ pf,
  const float* __restrict__ lc, const float* __restrict__ pc,
  const float* __restrict__ Wl, const float* __restrict__ bl,
  const float* __restrict__ Wp, const float* __restrict__ bp,
  const float* __restrict__ Wd1, const float* __restrict__ bd1,
  const float* __restrict__ Wd2, const float* __restrict__ bd2,
  const float* __restrict__ Wd3, const float* __restrict__ bd3,
  const float* __restrict__ Wgl, const float* __restrict__ bgl,
  const float* __restrict__ Wgp, const float* __restrict__ bgp,
  const float* __restrict__ Wqkv, const float* __restrict__ bqkv,
  const float* __restrict__ Wo, const float* __restrict__ bo,
  const float* __restrict__ g_l, const float* __restrict__ be_l,
  const float* __restrict__ g_p, const float* __restrict__ be_p,
  float* __restrict__ ws, float* __restrict__ out)
{
  cg::grid_group grd = cg::this_grid();
  const int b = blockIdx.x;
  const int t = threadIdx.x;

  __shared__ __align__(16) float smem[16384];   // 64 KB, aliased per phase

  float* WlT   = ws + WLT_OFF;
  float* WpT   = ws + WPT_OFF;
  float* WqkvT = ws + WQT_OFF;
  float* WoT   = ws + WOT_OFF;
  float* WglT  = ws + WGLT_OFF;
  float* WgpT  = ws + WGPT_OFF;
  float* tab   = ws + TAB_OFF;
  float* lig   = ws + LIG_OFF;
  float* poc   = ws + POC_OFF;
  float* lenh  = ws + LENH_OFF;
  float* penh  = ws + PENH_OFF;
  float* qkvl  = ws + QKVL_OFF;
  float* qkvp  = ws + QKVP_OFF;
  float* partL = ws + PARTL_OFF;
  float* partP = ws + PARTP_OFF;
  float* aggb  = ws + AGG_OFF;

  // ---------------- P0: weight transposes (163840 elements over 262144 threads) ----------------
  {
    int e = b*512 + t;
    if (e < 163840){
      if (e < 16384){
        int loc = e, o = loc >> 7, k = loc & 127;
        WlT[k*128 + o] = Wl[loc];
      } else if (e < 32768){
        int loc = e - 16384, o = loc >> 7, k = loc & 127;
        WpT[k*128 + o] = Wp[loc];
      } else if (e < 81920){
        int loc = e - 32768, o = loc >> 7, k = loc & 127;   // Wqkv [384][128]
        WqkvT[k*384 + o] = Wqkv[loc];
      } else if (e < 98304){
        int loc = e - 81920, o = loc >> 7, k = loc & 127;
        WoT[k*128 + o] = Wo[loc];
      } else if (e < 131072){
        int loc = e - 98304, o = loc >> 8, k = loc & 255;   // Wgl [128][256]
        WglT[k*128 + o] = Wgl[loc];
      } else {
        int loc = e - 131072, o = loc >> 8, k = loc & 255;
        WgpT[k*128 + o] = Wgp[loc];
      }
    }
  }
  grd.sync();

  // ---------------- P1: proj (blocks 0..383, 2 row-pair tasks each) + LUT (blocks 384..399) ----------------
  if (b < 384){
    int sub = t >> 8, st = t & 255;
    int s = b*2 + sub;                          // 0..767
    bool isLig = (s < NL/2);
    int r0 = isLig ? s*2 : (s - NL/2)*2;
    const float* in  = (isLig ? lf : pf) + (size_t)r0*HDIM;
    const float* WT  = isLig ? WlT : WpT;
    const float* bia = isLig ? bl : bp;
    float* o = (isLig ? lig : poc) + (size_t)r0*HDIM;
    float* sx = smem + sub*256;
    sx[st] = in[st];
    __syncthreads();
    int r = st >> 7, col = st & 127;
    const float* xr = sx + r*HDIM;
    float acc = bia[col];
    #pragma unroll 8
    for (int k = 0; k < 128; k++) acc = fmaf(WT[k*128 + col], xr[k], acc);
    o[r*HDIM + col] = acc;
  } else if (b < 400){
    // LUT: 512 entries per block, 16 blocks -> 8192 entries
    float* sWd1  = smem;          // 32
    float* sbd1  = smem + 32;     // 32
    float* sbd2  = smem + 64;     // 64
    float* swd3m = smem + 128;    // 64
    // smem[192] = sbd3m
    float* sWd2  = smem + 256;    // 2048
    if (t < 64){
      float ssum = 0.f;
      #pragma unroll 8
      for (int i = 0; i < 128; i++) ssum += Wd3[i*64 + t];
      swd3m[t] = ssum * (1.f/128.f);
    } else if (t == 64){
      float ssum = 0.f;
      for (int i = 0; i < 128; i++) ssum += bd3[i];
      smem[192] = ssum * (1.f/128.f);
    } else if (t >= 128 && t < 160){ sWd1[t-128] = Wd1[t-128]; sbd1[t-128] = bd1[t-128]; }
    else if (t >= 160 && t < 224){ sbd2[t-160] = bd2[t-160]; }
    for (int k = t; k < 2048; k += 512) sWd2[k] = Wd2[k];
    __syncthreads();

    int idx = (b - 384)*512 + t;
    float d = (float)idx * (DMAX / (float)(TAB_N - 1));
    float4 e1q[8];
    const float4* w1q = (const float4*)sWd1;
    const float4* b1q = (const float4*)sbd1;
    #pragma unroll
    for (int k4 = 0; k4 < 8; k4++){
      float4 w = w1q[k4], bb = b1q[k4];
      float4 e;
      e.x = fmaxf(fmaf(d, w.x, bb.x), 0.f);
      e.y = fmaxf(fmaf(d, w.y, bb.y), 0.f);
      e.z = fmaxf(fmaf(d, w.z, bb.z), 0.f);
      e.w = fmaxf(fmaf(d, w.w, bb.w), 0.f);
      e1q[k4] = e;
    }
    float mv = smem[192];
    #pragma unroll 4
    for (int j2 = 0; j2 < 64; j2++){
      const float4* wrow = (const float4*)(sWd2 + j2*32);
      float a0 = 0.f, a1 = 0.f, a2 = 0.f, a3 = 0.f;
      #pragma unroll
      for (int k4 = 0; k4 < 8; k4++){
        float4 w = wrow[k4], e = e1q[k4];
        a0 = fmaf(w.x, e.x, a0);
        a1 = fmaf(w.y, e.y, a1);
        a2 = fmaf(w.z, e.z, a2);
        a3 = fmaf(w.w, e.w, a3);
      }
      float e2v = fmaxf(sbd2[j2] + ((a0+a1)+(a2+a3)), 0.f);
      mv = fmaf(swd3m[j2], e2v, mv);
    }
    tab[idx] = mv;
  }
  grd.sync();

  // ---------------- P2a: softmax + aggregation. Balanced: b<256 -> 1 lig task; b>=256 -> 2 poc tasks ----------------
  {
    float*  w     = smem;                       // 2048 floats
    float4* part4 = (float4*)(smem + 2048);     // 512 float4 (2048 floats)
    float*  redm  = smem + 4096;                // 8
    float*  sgm   = smem + 4104;                // 2
    float*  sinv  = smem + 4106;                // 2

    int ntask = (b < 256) ? 1 : 2;
    bool isLig = (b < 256);
    int n = isLig ? NP : NL;
    const float* otherFeat = isLig ? poc : lig;
    const float* myC = isLig ? lc : pc;
    const float* otC = isLig ? pc : lc;
    int growbase = isLig ? 0 : NL;
    const float inv_h = (float)(TAB_N - 1) / DMAX;

    int rr = t >> 8, u = t & 255;
    int lane = t & 63, wv = t >> 6;
    int per = n >> 8;                           // 4 (lig) or 2 (poc)

    for (int it = 0; it < ntask; it++){
      int r0 = isLig ? b*2 : (2*(b-256) + it)*2;
      int row = r0 + rr;
      float cx = myC[row*3+0], cy = myC[row*3+1], cz = myC[row*3+2];

      float xs[4];
      float lmax = -1e30f;
      for (int k = 0; k < per; k++){
        int j = u + (k << 8);
        float ox = otC[j*3+0], oy = otC[j*3+1], oz = otC[j*3+2];
        float dx = cx-ox, dy = cy-oy, dz = cz-oz;
        float d = sqrtf(fmaf(dx,dx, fmaf(dy,dy, dz*dz)));
        float xf = d * inv_h;
        int i0 = (int)xf;
        i0 = (i0 > TAB_N-2) ? (TAB_N-2) : i0;
        float f = xf - (float)i0;
        float v0 = tab[i0], v1 = tab[i0+1];
        xs[k] = -fmaf(f, v1 - v0, v0);
        lmax = fmaxf(lmax, xs[k]);
      }
      float v = lmax;
      #pragma unroll
      for (int off = 32; off; off >>= 1) v = fmaxf(v, __shfl_down(v, off));
      if (lane == 0) redm[wv] = v;
      __syncthreads();
      if (t < 2) sgm[t] = fmaxf(fmaxf(redm[t*4+0], redm[t*4+1]), fmaxf(redm[t*4+2], redm[t*4+3]));
      __syncthreads();
      float gm = sgm[rr];
      float lsum = 0.f;
      for (int k = 0; k < per; k++){
        float e = __expf(xs[k] - gm);
        w[rr*NP + u + (k << 8)] = e;
        lsum += e;
      }
      v = lsum;
      #pragma unroll
      for (int off = 32; off; off >>= 1) v += __shfl_down(v, off);
      if (lane == 0) redm[wv] = v;
      __syncthreads();
      if (t < 2) sinv[t] = 1.0f / ((redm[t*4+0] + redm[t*4+1]) + (redm[t*4+2] + redm[t*4+3]));
      __syncthreads();

      // aggregation: 8 j-groups x 2 rows x 32 float4 cols
      {
        int jg = t >> 6;
        int r  = (t >> 5) & 1;
        int c4 = t & 31;
        int per2 = n >> 3;
        int jb0 = jg * per2;
        const float4* of4 = (const float4*)otherFeat;
        const float* wR = w + r*NP;
        float4 acc = {0,0,0,0};
        #pragma unroll 4
        for (int jj = 0; jj < per2; jj++){
          int j = jb0 + jj;
          float4 f = of4[(size_t)j*32 + c4];
          float ww = wR[j];
          acc.x = fmaf(ww, f.x, acc.x); acc.y = fmaf(ww, f.y, acc.y);
          acc.z = fmaf(ww, f.z, acc.z); acc.w = fmaf(ww, f.w, acc.w);
        }
        part4[(jg*2 + r)*32 + c4] = acc;
      }
      __syncthreads();
      #pragma unroll
      for (int s2 = 4; s2 >= 1; s2 >>= 1){
        if (t < s2*64){
          int g2 = t >> 6, rem = t & 63;
          float4 a = part4[g2*64 + rem], bb = part4[(g2+s2)*64 + rem];
          a.x += bb.x; a.y += bb.y; a.z += bb.z; a.w += bb.w;
          part4[g2*64 + rem] = a;
        }
        __syncthreads();
      }
      if (t < 256){
        float val = ((const float*)part4)[t] * sinv[t >> 7];
        aggb[(size_t)(growbase + r0 + (t >> 7))*HDIM + (t & 127)] = val;
      }
      __syncthreads();
    }
  }
  grd.sync();

  // ---------------- P2b: gate + enh + QKV, per-row (3 rows/block, uniform cost) ----------------
  {
    float* sx    = smem;          // 128
    float* sa2   = smem + 128;    // 128
    float* se    = smem + 256;    // 128
    float* gpart = smem + 384;    // 512
    for (int i = 0; i < 3; i++){
      int grow = b + i*512;                     // 0..1535
      bool isLig = (grow < NL);
      int row = isLig ? grow : grow - NL;
      const float* xsrc = (isLig ? lig : poc) + (size_t)row*HDIM;
      if (t < 128){ sx[t] = xsrc[t]; sa2[t] = aggb[(size_t)grow*HDIM + t]; }
      __syncthreads();
      {
        int col = t & 127, kg = t >> 7;          // kg 0..3 : k in [kg*64, kg*64+64)
        const float* WT = isLig ? WglT : WgpT;
        const float* inb = (kg < 2) ? sx : (sa2 - 128);
        int k0 = kg*64;
        float acc = 0.f;
        #pragma unroll 8
        for (int kk = 0; kk < 64; kk++){
          int k = k0 + kk;
          acc = fmaf(WT[(size_t)k*128 + col], inb[k], acc);
        }
        gpart[kg*128 + col] = acc;
      }
      __syncthreads();
      if (t < 128){
        const float* bg = isLig ? bgl : bgp;
        float g = bg[t] + ((gpart[t] + gpart[128+t]) + (gpart[256+t] + gpart[384+t]));
        g = 1.0f / (1.0f + __expf(-g));
        float xv = sx[t], av = sa2[t];
        float enh = fmaf(g, xv - av, av);
        se[t] = enh;
        float* dst = isLig ? (lenh + (size_t)row*HDIM) : (penh + (size_t)row*HDIM);
        dst[t] = enh;
      }
      __syncthreads();
      if (t < 384){
        float acc = bqkv[t];
        #pragma unroll 8
        for (int k = 0; k < 128; k++) acc = fmaf(WqkvT[(size_t)k*384 + t], se[k], acc);
        float* q = (isLig ? qkvl : qkvp) + (size_t)row*384;
        q[t] = acc;
      }
      __syncthreads();
    }
  }
  grd.sync();

  // ---------------- P3: flash attention, 1 task/block, 8 split-k groups x 16 keys ----------------
  {
    const float* qsrc; const float* kvsrc; int qt, slice; bool isLig;
    if (b < 256){ isLig = true;  qt = b >> 3; slice = b & 7; qsrc = qkvl; kvsrc = qkvp; }
    else { int b2 = b - 256; isLig = false; qt = b2 >> 2; slice = b2 & 3; qsrc = qkvp; kvsrc = qkvl; }
    int g = t >> 6, tt = t & 63;
    int h = tt >> 3, qp = tt & 7;
    int j0 = slice*128 + g*16;

    const float4* qA = (const float4*)(qsrc + (size_t)(qt*16+qp)*384 + h*16);
    const float4* qB = (const float4*)(qsrc + (size_t)(qt*16+qp+8)*384 + h*16);
    float4 a0 = qA[0], a1 = qA[1], a2 = qA[2], a3 = qA[3];
    float4 b0 = qB[0], b1 = qB[1], b2 = qB[2], b3 = qB[3];
    float mA = -1e30f, lA = 0.f, mB = -1e30f, lB = 0.f;
    float4 OA0={0,0,0,0}, OA1={0,0,0,0}, OA2={0,0,0,0}, OA3={0,0,0,0};
    float4 OB0={0,0,0,0}, OB1={0,0,0,0}, OB2={0,0,0,0}, OB3={0,0,0,0};

    float* myKV = smem + g*2048;                 // 8 keys x 256 floats

    for (int tile = 0; tile < 2; tile++){
      int jbase = j0 + tile*8;
      __syncthreads();
      #pragma unroll
      for (int nn = 0; nn < 8; nn++){
        int v4 = tt + nn*64;
        int jj = v4 >> 6, c4 = v4 & 63;
        ((float4*)myKV)[jj*64 + c4] = *(const float4*)(kvsrc + (size_t)(jbase+jj)*384 + 128 + c4*4);
      }
      __syncthreads();
      float sA[8], sB[8];
      #pragma unroll
      for (int jj = 0; jj < 8; jj++){
        const float4* kk = (const float4*)(myKV + jj*256 + h*16);
        float4 k0 = kk[0], k1 = kk[1], k2 = kk[2], k3 = kk[3];
        sA[jj] = (dot4f(a0,k0) + dot4f(a1,k1) + dot4f(a2,k2) + dot4f(a3,k3)) * 0.25f;
        sB[jj] = (dot4f(b0,k0) + dot4f(b1,k1) + dot4f(b2,k2) + dot4f(b3,k3)) * 0.25f;
      }
      float mtA = sA[0], mtB = sB[0];
      #pragma unroll
      for (int jj = 1; jj < 8; jj++){ mtA = fmaxf(mtA, sA[jj]); mtB = fmaxf(mtB, sB[jj]); }
      float mnA = fmaxf(mA, mtA), mnB = fmaxf(mB, mtB);
      float cA = __expf(mA - mnA), cB = __expf(mB - mnB);
      lA *= cA; lB *= cB;
      OA0.x*=cA; OA0.y*=cA; OA0.z*=cA; OA0.w*=cA;
      OA1.x*=cA; OA1.y*=cA; OA1.z*=cA; OA1.w*=cA;
      OA2.x*=cA; OA2.y*=cA; OA2.z*=cA; OA2.w*=cA;
      OA3.x*=cA; OA3.y*=cA; OA3.z*=cA; OA3.w*=cA;
      OB0.x*=cB; OB0.y*=cB; OB0.z*=cB; OB0.w*=cB;
      OB1.x*=cB; OB1.y*=cB; OB1.z*=cB; OB1.w*=cB;
      OB2.x*=cB; OB2.y*=cB; OB2.z*=cB; OB2.w*=cB;
      OB3.x*=cB; OB3.y*=cB; OB3.z*=cB; OB3.w*=cB;
      #pragma unroll
      for (int jj = 0; jj < 8; jj++){
        float pA = __expf(sA[jj] - mnA);
        float pB = __expf(sB[jj] - mnB);
        lA += pA; lB += pB;
        const float4* vv = (const float4*)(myKV + jj*256 + 128 + h*16);
        float4 v0 = vv[0], v1 = vv[1], v2 = vv[2], v3 = vv[3];
        OA0.x = fmaf(pA, v0.x, OA0.x); OA0.y = fmaf(pA, v0.y, OA0.y);
        OA0.z = fmaf(pA, v0.z, OA0.z); OA0.w = fmaf(pA, v0.w, OA0.w);
        OA1.x = fmaf(pA, v1.x, OA1.x); OA1.y = fmaf(pA, v1.y, OA1.y);
        OA1.z = fmaf(pA, v1.z, OA1.z); OA1.w = fmaf(pA, v1.w, OA1.w);
        OA2.x = fmaf(pA, v2.x, OA2.x); OA2.y = fmaf(pA, v2.y, OA2.y);
        OA2.z = fmaf(pA, v2.z, OA2.z); OA2.w = fmaf(pA, v2.w, OA2.w);
        OA3.x = fmaf(pA, v3.x, OA3.x); OA3.y = fmaf(pA, v3.y, OA3.y);
        OA3.z = fmaf(pA, v3.z, OA3.z); OA3.w = fmaf(pA, v3.w, OA3.w);
        OB0.x = fmaf(pB, v0.x, OB0.x); OB0.y = fmaf(pB, v0.y, OB0.y);
        OB0.z = fmaf(pB, v0.z, OB0.z); OB0.w = fmaf(pB, v0.w, OB0.w);
        OB1.x = fmaf(pB, v1.x, OB1.x); OB1.y = fmaf(pB, v1.y, OB1.y);
        OB1.z = fmaf(pB, v1.z, OB1.z); OB1.w = fmaf(pB, v1.w, OB1.w);
        OB2.x = fmaf(pB, v2.x, OB2.x); OB2.y = fmaf(pB, v2.y, OB2.y);
        OB2.z = fmaf(pB, v2.z, OB2.z); OB2.w = fmaf(pB, v2.w, OB2.w);
        OB3.x = fmaf(pB, v3.x, OB3.x); OB3.y = fmaf(pB, v3.y, OB3.y);
        OB3.z = fmaf(pB, v3.z, OB3.z); OB3.w = fmaf(pB, v3.w, OB3.w);
      }
      mA = mnA; mB = mnB;
    }

    __syncthreads();
    if (g > 0){
      float* bA = smem + (size_t)((g-1)*128 + tt*2)*18;
      bA[0]=mA; bA[1]=lA;
      bA[2]=OA0.x; bA[3]=OA0.y; bA[4]=OA0.z; bA[5]=OA0.w;
      bA[6]=OA1.x; bA[7]=OA1.y; bA[8]=OA1.z; bA[9]=OA1.w;
      bA[10]=OA2.x; bA[11]=OA2.y; bA[12]=OA2.z; bA[13]=OA2.w;
      bA[14]=OA3.x; bA[15]=OA3.y; bA[16]=OA3.z; bA[17]=OA3.w;
      float* bB = bA + 18;
      bB[0]=mB; bB[1]=lB;
      bB[2]=OB0.x; bB[3]=OB0.y; bB[4]=OB0.z; bB[5]=OB0.w;
      bB[6]=OB1.x; bB[7]=OB1.y; bB[8]=OB1.z; bB[9]=OB1.w;
      bB[10]=OB2.x; bB[11]=OB2.y; bB[12]=OB2.z; bB[13]=OB2.w;
      bB[14]=OB3.x; bB[15]=OB3.y; bB[16]=OB3.z; bB[17]=OB3.w;
    }
    __syncthreads();
    if (g == 0){
      float M = mA, L = lA;
      float O[16] = {OA0.x,OA0.y,OA0.z,OA0.w, OA1.x,OA1.y,OA1.z,OA1.w,
                     OA2.x,OA2.y,OA2.z,OA2.w, OA3.x,OA3.y,OA3.z,OA3.w};
      #pragma unroll
      for (int gg = 1; gg < 8; gg++){
        const float* br = smem + (size_t)((gg-1)*128 + tt*2)*18;
        float m1 = br[0], l1 = br[1];
        float Mn = fmaxf(M, m1);
        float e0 = __expf(M - Mn), e1 = __expf(m1 - Mn);
        L = L*e0 + l1*e1;
        #pragma unroll
        for (int k = 0; k < 16; k++) O[k] = O[k]*e0 + br[2+k]*e1;
        M = Mn;
      }
      int rowA = qt*16 + qp;
      float* dst = isLig ? (partL + ((size_t)(rowA*8 + h)*8 + slice)*18)
                         : (partP + ((size_t)(rowA*8 + h)*4 + slice)*18);
      dst[0] = M; dst[1] = L;
      #pragma unroll
      for (int k = 0; k < 16; k++) dst[2+k] = O[k];
      M = mB; L = lB;
      float Ob[16] = {OB0.x,OB0.y,OB0.z,OB0.w, OB1.x,OB1.y,OB1.z,OB1.w,
                      OB2.x,OB2.y,OB2.z,OB2.w, OB3.x,OB3.y,OB3.z,OB3.w};
      #pragma unroll
      for (int gg = 1; gg < 8; gg++){
        const float* br = smem + (size_t)((gg-1)*128 + tt*2)*18 + 18;
        float m1 = br[0], l1 = br[1];
        float Mn = fmaxf(M, m1);
        float e0 = __expf(M - Mn), e1 = __expf(m1 - Mn);
        L = L*e0 + l1*e1;
        #pragma unroll
        for (int k = 0; k < 16; k++) Ob[k] = Ob[k]*e0 + br[2+k]*e1;
        M = Mn;
      }
      int rowB = qt*16 + qp + 8;
      float* dstB = isLig ? (partL + ((size_t)(rowB*8 + h)*8 + slice)*18)
                          : (partP + ((size_t)(rowB*8 + h)*4 + slice)*18);
      dstB[0] = M; dstB[1] = L;
      #pragma unroll
      for (int k = 0; k < 16; k++) dstB[2+k] = Ob[k];
    }
  }
  grd.sync();

  // ---------------- P4: merge partials + Wo proj + residual + LayerNorm (768 tasks over 1024 subgroups) ----------------
  {
    int sub = t >> 8, st = t & 255;
    int s = b*2 + sub;
    if (s < 768){
      int r0 = s*2;
      int r = st >> 7, c = st & 127;
      int gr = r0 + r;
      int hh = c >> 4, cc = c & 15;
      int ns; const float* base;
      if (gr < NL){ ns = 8; base = partL + ((size_t)(gr*8 + hh))*8*18; }
      else        { ns = 4; base = partP + ((size_t)((gr-NL)*8 + hh))*4*18; }
      float M = -1e30f;
      for (int sl = 0; sl < ns; sl++) M = fmaxf(M, base[sl*18]);
      float Lsum = 0.f, Osum = 0.f;
      for (int sl = 0; sl < ns; sl++){
        float e = __expf(base[sl*18] - M);
        Lsum = fmaf(e, base[sl*18+1], Lsum);
        Osum = fmaf(e, base[sl*18+2+cc], Osum);
      }
      float* sAtt = smem + sub*512;           // 256 used
      float* sred = smem + 1024 + sub*16;     // 8 used
      sAtt[st] = Osum / Lsum;
      __syncthreads();
      float o = bo[c];
      const float* sA = sAtt + r*HDIM;
      #pragma unroll 8
      for (int k = 0; k < 128; k++) o = fmaf(WoT[k*128 + c], sA[k], o);
      const float* enh = (gr < NL) ? (lenh + (size_t)gr*HDIM) : (penh + (size_t)(gr-NL)*HDIM);
      float x = enh[c] + o;
      int wid = st >> 6;
      float v = x;
      #pragma unroll
      for (int off = 32; off; off >>= 1) v += __shfl_down(v, off);
      if ((st & 63) == 0) sred[wid] = v;
      __syncthreads();
      float mu = (sred[2*r] + sred[2*r+1]) * (1.f/128.f);
      float dx = x - mu;
      v = dx*dx;
      #pragma unroll
      for (int off = 32; off; off >>= 1) v += __shfl_down(v, off);
      if ((st & 63) == 0) sred[4 + wid] = v;
      __syncthreads();
      float var = (sred[4 + 2*r] + sred[4 + 2*r+1]) * (1.f/128.f);
      float y = dx * rsqrtf(var + 1e-5f);
      if (gr < NL) y = fmaf(y, g_l[c], be_l[c]);
      else         y = fmaf(y, g_p[c], be_p[c]);
      out[(size_t)gr*HDIM + c] = y;
    }
  }
}

// =====================================================================================
// Fallback path: the proven 5-kernel pipeline (used only if cooperative launch fails)
// =====================================================================================
__device__ __forceinline__ void tpose(const float* __restrict__ src, float* __restrict__ dst,
                                      int O, int K, int blk0, int t){
  int e0 = blk0*1024 + t*4;
  #pragma unroll
  for (int i = 0; i < 4; i++){
    int e = e0 + i;
    int o = e / K, k = e - o*K;
    dst[(size_t)k*O + o] = src[(size_t)o*K + k];
  }
}
__global__ __launch_bounds__(256) void prep_all(const float* __restrict__ Wl, const float* __restrict__ Wp,
                                                const float* __restrict__ Wqkv, const float* __restrict__ Wo,
                                                const float* __restrict__ Wgl, const float* __restrict__ Wgp,
                                                const float* __restrict__ Wd1, const float* __restrict__ bd1,
                                                const float* __restrict__ Wd2, const float* __restrict__ bd2,
                                                const float* __restrict__ Wd3, const float* __restrict__ bd3,
                                                float* __restrict__ ws){
  int b = blockIdx.x, t = threadIdx.x;
  if (b < 160){
    if      (b < 16)  tpose(Wl,   ws + WLT_OFF,  128, 128, b,       t);
    else if (b < 32)  tpose(Wp,   ws + WPT_OFF,  128, 128, b - 16,  t);
    else if (b < 80)  tpose(Wqkv, ws + WQT_OFF,  384, 128, b - 32,  t);
    else if (b < 96)  tpose(Wo,   ws + WOT_OFF,  128, 128, b - 80,  t);
    else if (b < 128) tpose(Wgl,  ws + WGLT_OFF, 128, 256, b - 96,  t);
    else              tpose(Wgp,  ws + WGPT_OFF, 128, 256, b - 128, t);
    return;
  }
  float* tab = ws + TAB_OFF;
  __shared__ float sWd1[32], sbd1[32], sWd2[2048], sbd2[64], swd3m[64];
  __shared__ float sbd3m;
  int idx = (b - 160) * 256 + t;
  if (t < 64){
    float s = 0.f;
    #pragma unroll 8
    for (int i = 0; i < 128; i++) s += Wd3[i*64 + t];
    swd3m[t] = s * (1.f/128.f);
  } else if (t == 64){
    float s = 0.f;
    for (int i = 0; i < 128; i++) s += bd3[i];
    sbd3m = s * (1.f/128.f);
  } else if (t >= 128 && t < 160){ sWd1[t-128] = Wd1[t-128]; sbd1[t-128] = bd1[t-128]; }
  else if (t >= 160 && t < 224){ sbd2[t-160] = bd2[t-160]; }
  for (int k = t; k < 2048; k += 256) sWd2[k] = Wd2[k];
  __syncthreads();

  float d = (float)idx * (DMAX / (float)(TAB_N - 1));
  float4 e1q[8];
  const float4* w1q = (const float4*)sWd1;
  const float4* b1q = (const float4*)sbd1;
  #pragma unroll
  for (int k4 = 0; k4 < 8; k4++){
    float4 w = w1q[k4], bb = b1q[k4];
    float4 e;
    e.x = fmaxf(fmaf(d, w.x, bb.x), 0.f);
    e.y = fmaxf(fmaf(d, w.y, bb.y), 0.f);
    e.z = fmaxf(fmaf(d, w.z, bb.z), 0.f);
    e.w = fmaxf(fmaf(d, w.w, bb.w), 0.f);
    e1q[k4] = e;
  }
  float mv = sbd3m;
  #pragma unroll 4
  for (int j2 = 0; j2 < 64; j2++){
    const float4* wrow = (const float4*)(sWd2 + j2*32);
    float a0 = 0.f, a1 = 0.f, a2 = 0.f, a3 = 0.f;
    #pragma unroll
    for (int k4 = 0; k4 < 8; k4++){
      float4 w = wrow[k4], e = e1q[k4];
      a0 = fmaf(w.x, e.x, a0);
      a1 = fmaf(w.y, e.y, a1);
      a2 = fmaf(w.z, e.z, a2);
      a3 = fmaf(w.w, e.w, a3);
    }
    float e2v = fmaxf(sbd2[j2] + ((a0+a1)+(a2+a3)), 0.f);
    mv = fmaf(swd3m[j2], e2v, mv);
  }
  tab[idx] = mv;
}

__global__ __launch_bounds__(256) void proj_kernel(const float* __restrict__ lf, const float* __restrict__ pf,
                                                   const float* __restrict__ WlT, const float* __restrict__ bl,
                                                   const float* __restrict__ WpT, const float* __restrict__ bp,
                                                   float* __restrict__ lig, float* __restrict__ poc){
  int b = blockIdx.x, t = threadIdx.x;
  bool isLig = (b < NL/2);
  int r0 = isLig ? b*2 : (b - NL/2)*2;
  const float* in = (isLig ? lf : pf) + (size_t)r0*HDIM;
  const float* WT = isLig ? WlT : WpT;
  const float* bias = isLig ? bl : bp;
  float* out = (isLig ? lig : poc) + (size_t)r0*HDIM;
  __shared__ float sx[2*HDIM];
  sx[t] = in[t];
  __syncthreads();
  int r = t >> 7, col = t & 127;
  const float* xr = sx + r*HDIM;
  float acc = bias[col];
  #pragma unroll 8
  for (int k = 0; k < 128; k++) acc = fmaf(WT[k*128 + col], xr[k], acc);
  out[r*HDIM + col] = acc;
}

__global__ __launch_bounds__(512) void agg_gate_fused(const float* __restrict__ lc, const float* __restrict__ pc,
                                                      const float* __restrict__ tab,
                                                      const float* __restrict__ lig, const float* __restrict__ poc,
                                                      const float* __restrict__ WglT, const float* __restrict__ bgl,
                                                      const float* __restrict__ WgpT, const float* __restrict__ bgp,
                                                      const float* __restrict__ WqkvT, const float* __restrict__ bqkv,
                                                      float* __restrict__ lenh, float* __restrict__ penh,
                                                      float* __restrict__ qkvl, float* __restrict__ qkvp){
  int b = blockIdx.x, t = threadIdx.x;
  bool isLig = (b < NL/2);
  int r0 = isLig ? b*2 : (b - NL/2)*2;
  int n = isLig ? NP : NL;
  const float* myFeat = isLig ? lig : poc;
  const float* otherFeat = isLig ? poc : lig;
  const float* myC = isLig ? lc : pc;
  const float* otC = isLig ? pc : lc;

  __shared__ float w[2*NP];
  __shared__ float sx[2*HDIM];
  __shared__ float sa[2*HDIM];
  __shared__ float4 part4[8*64];
  __shared__ float gpart[512];
  __shared__ float redm[8];
  __shared__ float sgm[2], sinv[2];

  int rr = t >> 8, u = t & 255;
  int lane = t & 63, wv = t >> 6;
  int row = r0 + rr;

  if (t < 256) sx[t] = myFeat[(size_t)r0*HDIM + t];

  float cx = myC[row*3+0], cy = myC[row*3+1], cz = myC[row*3+2];
  const float inv_h = (float)(TAB_N - 1) / DMAX;
  int per = n >> 8;

  float xs[4];
  float lmax = -1e30f;
  for (int k = 0; k < per; k++){
    int j = u + (k << 8);
    float ox = otC[j*3+0], oy = otC[j*3+1], oz = otC[j*3+2];
    float dx = cx-ox, dy = cy-oy, dz = cz-oz;
    float d = sqrtf(fmaf(dx,dx, fmaf(dy,dy, dz*dz)));
    float xf = d * inv_h;
    int i0 = (int)xf;
    i0 = (i0 > TAB_N-2) ? (TAB_N-2) : i0;
    float f = xf - (float)i0;
    float v0 = tab[i0], v1 = tab[i0+1];
    xs[k] = -fmaf(f, v1 - v0, v0);
    lmax = fmaxf(lmax, xs[k]);
  }
  float v = lmax;
  #pragma unroll
  for (int off = 32; off; off >>= 1) v = fmaxf(v, __shfl_down(v, off));
  if (lane == 0) redm[wv] = v;
  __syncthreads();
  if (t < 2) sgm[t] = fmaxf(fmaxf(redm[t*4+0], redm[t*4+1]), fmaxf(redm[t*4+2], redm[t*4+3]));
  __syncthreads();
  float gm = sgm[rr];
  float lsum = 0.f;
  for (int k = 0; k < per; k++){
    float e = __expf(xs[k] - gm);
    w[rr*NP + u + (k << 8)] = e;
    lsum += e;
  }
  v = lsum;
  #pragma unroll
  for (int off = 32; off; off >>= 1) v += __shfl_down(v, off);
  if (lane == 0) redm[wv] = v;
  __syncthreads();
  if (t < 2) sinv[t] = 1.0f / ((redm[t*4+0] + redm[t*4+1]) + (redm[t*4+2] + redm[t*4+3]));
  __syncthreads();

  {
    int jg = t >> 6;
    int r  = (t >> 5) & 1;
    int c4 = t & 31;
    int per2 = n >> 3;
    int jb0 = jg * per2;
    const float4* of4 = (const float4*)otherFeat;
    const float* wR = w + r*NP;
    float4 acc = {0,0,0,0};
    #pragma unroll 4
    for (int jj = 0; jj < per2; jj++){
      int j = jb0 + jj;
      float4 f = of4[(size_t)j*32 + c4];
      float ww = wR[j];
      acc.x = fmaf(ww, f.x, acc.x); acc.y = fmaf(ww, f.y, acc.y);
      acc.z = fmaf(ww, f.z, acc.z); acc.w = fmaf(ww, f.w, acc.w);
    }
    part4[(jg*2 + r)*32 + c4] = acc;
  }
  __syncthreads();
  #pragma unroll
  for (int s = 4; s >= 1; s >>= 1){
    if (t < s*64){
      int g2 = t >> 6, rem = t & 63;
      float4 a = part4[g2*64 + rem], bb = part4[(g2+s)*64 + rem];
      a.x += bb.x; a.y += bb.y; a.z += bb.z; a.w += bb.w;
      part4[g2*64 + rem] = a;
    }
    __syncthreads();
  }
  if (t < 256) sa[t] = ((const float*)part4)[t] * sinv[t >> 7];
  __syncthreads();

  {
    int r  = t >> 8;
    int kg = (t >> 7) & 1;
    int col = t & 127;
    const float* WT = isLig ? WglT : WgpT;
    const float* inq = (kg == 0) ? (sx + r*HDIM) : (sa + r*HDIM);
    const float* wbase = WT + (size_t)kg*128*128;
    float g = 0.f;
    #pragma unroll 8
    for (int k = 0; k < 128; k++) g = fmaf(wbase[k*128 + col], inq[k], g);
    gpart[kg*256 + r*128 + col] = g;
  }
  __syncthreads();
  float enh_val = 0.f;
  if (t < 256){
    int r = t >> 7, col = t & 127;
    const float* bg = isLig ? bgl : bgp;
    float g = bg[col] + gpart[t] + gpart[256 + t];
    g = 1.0f / (1.0f + __expf(-g));
    float xv = sx[t], av = sa[t];
    enh_val = fmaf(g, xv - av, av);
    float* dst = isLig ? (lenh + (size_t)(r0+r)*HDIM) : (penh + (size_t)(r0+r)*HDIM);
    dst[col] = enh_val;
  }
  __syncthreads();
  if (t < 256) sa[t] = enh_val;
  __syncthreads();

  {
    int r = t >> 8, ln = t & 255;
    const float* er = sa + r*HDIM;
    float* qout = (isLig ? qkvl : qkvp) + (size_t)(r0+r)*384;
    if (ln < 128){
      float a0 = bqkv[ln], a2 = bqkv[ln+256];
      #pragma unroll 4
      for (int k = 0; k < 128; k++){
        float xv = er[k];
        const float* wk = WqkvT + k*384;
        a0 = fmaf(wk[ln],     xv, a0);
        a2 = fmaf(wk[ln+256], xv, a2);
      }
      qout[ln] = a0; qout[ln+256] = a2;
    } else {
      float a1 = bqkv[ln];
      #pragma unroll 4
      for (int k = 0; k < 128; k++) a1 = fmaf(WqkvT[k*384 + ln], er[k], a1);
      qout[ln] = a1;
    }
  }
}

__global__ __launch_bounds__(256) void attn_part(const float* __restrict__ qkvl, const float* __restrict__ qkvp,
                                                 float* __restrict__ partL, float* __restrict__ partP){
  int bx = blockIdx.x;
  int t = threadIdx.x;
  const float* qsrc; const float* kvsrc; int qt, slice; bool isLig;
  if (bx < 256){ isLig = true;  qt = bx >> 3; slice = bx & 7; qsrc = qkvl; kvsrc = qkvp; }
  else { int b2 = bx - 256; isLig = false; qt = b2 >> 2; slice = b2 & 3; qsrc = qkvp; kvsrc = qkvl; }
  int g = t >> 6, tt = t & 63;
  int h = tt >> 3, qp = tt & 7;
  int j0 = slice*128 + g*32;

  const float4* qA = (const float4*)(qsrc + (size_t)(qt*16+qp)*384 + h*16);
  const float4* qB = (const float4*)(qsrc + (size_t)(qt*16+qp+8)*384 + h*16);
  float4 a0 = qA[0], a1 = qA[1], a2 = qA[2], a3 = qA[3];
  float4 b0 = qB[0], b1 = qB[1], b2 = qB[2], b3 = qB[3];
  float mA = -1e30f, lA = 0.f, mB = -1e30f, lB = 0.f;
  float4 OA0={0,0,0,0}, OA1={0,0,0,0}, OA2={0,0,0,0}, OA3={0,0,0,0};
  float4 OB0={0,0,0,0}, OB1={0,0,0,0}, OB2={0,0,0,0}, OB3={0,0,0,0};

  __shared__ float sKV[8192];
  float* myKV = sKV + g*2048;

  for (int tile = 0; tile < 4; tile++){
    int jbase = j0 + tile*8;
    __syncthreads();
    #pragma unroll
    for (int nn = 0; nn < 8; nn++){
      int v4 = tt + nn*64;
      int jj = v4 >> 6, c4 = v4 & 63;
      ((float4*)myKV)[jj*64 + c4] = *(const float4*)(kvsrc + (size_t)(jbase+jj)*384 + 128 + c4*4);
    }
    __syncthreads();
    float sA[8], sB[8];
    #pragma unroll
    for (int jj = 0; jj < 8; jj++){
      const float4* kk = (const float4*)(myKV + jj*256 + h*16);
      float4 k0 = kk[0], k1 = kk[1], k2 = kk[2], k3 = kk[3];
      sA[jj] = (dot4f(a0,k0) + dot4f(a1,k1) + dot4f(a2,k2) + dot4f(a3,k3)) * 0.25f;
      sB[jj] = (dot4f(b0,k0) + dot4f(b1,k1) + dot4f(b2,k2) + dot4f(b3,k3)) * 0.25f;
    }
    float mtA = sA[0], mtB = sB[0];
    #pragma unroll
    for (int jj = 1; jj < 8; jj++){ mtA = fmaxf(mtA, sA[jj]); mtB = fmaxf(mtB, sB[jj]); }
    float mnA = fmaxf(mA, mtA), mnB = fmaxf(mB, mtB);
    float cA = __expf(mA - mnA), cB = __expf(mB - mnB);
    lA *= cA; lB *= cB;
    OA0.x*=cA; OA0.y*=cA; OA0.z*=cA; OA0.w*=cA;
    OA1.x*=cA; OA1.y*=cA; OA1.z*=cA; OA1.w*=cA;
    OA2.x*=cA; OA2.y*=cA; OA2.z*=cA; OA2.w*=cA;
    OA3.x*=cA; OA3.y*=cA; OA3.z*=cA; OA3.w*=cA;
    OB0.x*=cB; OB0.y*=cB; OB0.z*=cB; OB0.w*=cB;
    OB1.x*=cB; OB1.y*=cB; OB1.z*=cB; OB1.w*=cB;
    OB2.x*=cB; OB2.y*=cB; OB2.z*=cB; OB2.w*=cB;
    OB3.x*=cB; OB3.y*=cB; OB3.z*=cB; OB3.w*=cB;
    #pragma unroll
    for (int jj = 0; jj < 8; jj++){
      float pA = __expf(sA[jj] - mnA);
      float pB = __expf(sB[jj] - mnB);
      lA += pA; lB += pB;
      const float4* vv = (const float4*)(myKV + jj*256 + 128 + h*16);
      float4 v0 = vv[0], v1 = vv[1], v2 = vv[2], v3 = vv[3];
      OA0.x = fmaf(pA, v0.x, OA0.x); OA0.y = fmaf(pA, v0.y, OA0.y);
      OA0.z = fmaf(pA, v0.z, OA0.z); OA0.w = fmaf(pA, v0.w, OA0.w);
      OA1.x = fmaf(pA, v1.x, OA1.x); OA1.y = fmaf(pA, v1.y, OA1.y);
      OA1.z = fmaf(pA, v1.z, OA1.z); OA1.w = fmaf(pA, v1.w, OA1.w);
      OA2.x = fmaf(pA, v2.x, OA2.x); OA2.y = fmaf(pA, v2.y, OA2.y);
      OA2.z = fmaf(pA, v2.z, OA2.z); OA2.w = fmaf(pA, v2.w, OA2.w);
      OA3.x = fmaf(pA, v3.x, OA3.x); OA3.y = fmaf(pA, v3.y, OA3.y);
      OA3.z = fmaf(pA, v3.z, OA3.z); OA3.w = fmaf(pA, v3.w, OA3.w);
      OB0.x = fmaf(pB, v0.x, OB0.x); OB0.y = fmaf(pB, v0.y, OB0.y);
      OB0.z = fmaf(pB, v0.z, OB0.z); OB0.w = fmaf(pB, v0.w, OB0.w);
      OB1.x = fmaf(pB, v1.x, OB1.x); OB1.y = fmaf(pB, v1.y, OB1.y);
      OB1.z = fmaf(pB, v1.z, OB1.z); OB1.w = fmaf(pB, v1.w, OB1.w);
      OB2.x = fmaf(pB, v2.x, OB2.x); OB2.y = fmaf(pB, v2.y, OB2.y);
      OB2.z = fmaf(pB, v2.z, OB2.z); OB2.w = fmaf(pB, v2.w, OB2.w);
      OB3.x = fmaf(pB, v3.x, OB3.x); OB3.y = fmaf(pB, v3.y, OB3.y);
      OB3.z = fmaf(pB, v3.z, OB3.z); OB3.w = fmaf(pB, v3.w, OB3.w);
    }
    mA = mnA; mB = mnB;
  }

  __syncthreads();
  if (g > 0){
    float* bA = sKV + (size_t)((g-1)*128 + tt*2)*19;
    bA[0]=mA; bA[1]=lA;
    bA[2]=OA0.x; bA[3]=OA0.y; bA[4]=OA0.z; bA[5]=OA0.w;
    bA[6]=OA1.x; bA[7]=OA1.y; bA[8]=OA1.z; bA[9]=OA1.w;
    bA[10]=OA2.x; bA[11]=OA2.y; bA[12]=OA2.z; bA[13]=OA2.w;
    bA[14]=OA3.x; bA[15]=OA3.y; bA[16]=OA3.z; bA[17]=OA3.w;
    float* bB = bA + 19;
    bB[0]=mB; bB[1]=lB;
    bB[2]=OB0.x; bB[3]=OB0.y; bB[4]=OB0.z; bB[5]=OB0.w;
    bB[6]=OB1.x; bB[7]=OB1.y; bB[8]=OB1.z; bB[9]=OB1.w;
    bB[10]=OB2.x; bB[11]=OB2.y; bB[12]=OB2.z; bB[13]=OB2.w;
    bB[14]=OB3.x; bB[15]=OB3.y; bB[16]=OB3.z; bB[17]=OB3.w;
  }
  __syncthreads();
  if (g == 0){
    float M = mA, L = lA;
    float O[16] = {OA0.x,OA0.y,OA0.z,OA0.w, OA1.x,OA1.y,OA1.z,OA1.w,
                   OA2.x,OA2.y,OA2.z,OA2.w, OA3.x,OA3.y,OA3.z,OA3.w};
    #pragma unroll
    for (int gg = 1; gg < 4; gg++){
      const float* br = sKV + (size_t)((gg-1)*128 + tt*2)*19;
      float m1 = br[0], l1 = br[1];
      float Mn = fmaxf(M, m1);
      float e0 = __expf(M - Mn), e1 = __expf(m1 - Mn);
      L = L*e0 + l1*e1;
      #pragma unroll
      for (int k = 0; k < 16; k++) O[k] = O[k]*e0 + br[2+k]*e1;
      M = Mn;
    }
    int rowA = qt*16 + qp;
    float* dst = isLig ? (partL + ((size_t)(rowA*8 + h)*8 + slice)*18)
                       : (partP + ((size_t)(rowA*8 + h)*4 + slice)*18);
    dst[0] = M; dst[1] = L;
    #pragma unroll
    for (int k = 0; k < 16; k++) dst[2+k] = O[k];
    M = mB; L = lB;
    float Ob[16] = {OB0.x,OB0.y,OB0.z,OB0.w, OB1.x,OB1.y,OB1.z,OB1.w,
                    OB2.x,OB2.y,OB2.z,OB2.w, OB3.x,OB3.y,OB3.z,OB3.w};
    #pragma unroll
    for (int gg = 1; gg < 4; gg++){
      const float* br = sKV + (size_t)((gg-1)*128 + tt*2 + 1)*19;
      float m1 = br[0], l1 = br[1];
      float Mn = fmaxf(M, m1);
      float e0 = __expf(M - Mn), e1 = __expf(m1 - Mn);
      L = L*e0 + l1*e1;
      #pragma unroll
      for (int k = 0; k < 16; k++) Ob[k] = Ob[k]*e0 + br[2+k]*e1;
      M = Mn;
    }
    int rowB = qt*16 + qp + 8;
    float* dstB = isLig ? (partL + ((size_t)(rowB*8 + h)*8 + slice)*18)
                        : (partP + ((size_t)(rowB*8 + h)*4 + slice)*18);
    dstB[0] = M; dstB[1] = L;
    #pragma unroll
    for (int k = 0; k < 16; k++) dstB[2+k] = Ob[k];
  }
}

__global__ __launch_bounds__(256) void merge_ln(const float* __restrict__ partL, const float* __restrict__ partP,
                                                const float* __restrict__ lenh, const float* __restrict__ penh,
                                                const float* __restrict__ WoT, const float* __restrict__ bo,
                                                const float* __restrict__ g_l, const float* __restrict__ be_l,
                                                const float* __restrict__ g_p, const float* __restrict__ be_p,
                                                float* __restrict__ out){
  int b = blockIdx.x, t = threadIdx.x;
  int r0 = b*2;
  int r = t >> 7, c = t & 127;
  int gr = r0 + r;
  int h = c >> 4, cc = c & 15;
  int ns; const float* base;
  if (gr < NL){ ns = 8; base = partL + ((size_t)(gr*8 + h))*8*18; }
  else        { ns = 4; base = partP + ((size_t)((gr-NL)*8 + h))*4*18; }
  float M = -1e30f;
  for (int s = 0; s < ns; s++) M = fmaxf(M, base[s*18]);
  float Lsum = 0.f, Osum = 0.f;
  for (int s = 0; s < ns; s++){
    float e = __expf(base[s*18] - M);
    Lsum = fmaf(e, base[s*18+1], Lsum);
    Osum = fmaf(e, base[s*18+2+cc], Osum);
  }
  __shared__ float sAtt[2*HDIM];
  sAtt[t] = Osum / Lsum;
  __syncthreads();
  float o = bo[c];
  const float* sA = sAtt + r*HDIM;
  #pragma unroll 8
  for (int k = 0; k < 128; k++) o = fmaf(WoT[k*128 + c], sA[k], o);
  const float* enh = (gr < NL) ? (lenh + (size_t)gr*HDIM) : (penh + (size_t)(gr-NL)*HDIM);
  float x = enh[c] + o;
  __shared__ float sred[8];
  int wid = t >> 6;
  float v = x;
  #pragma unroll
  for (int off = 32; off; off >>= 1) v += __shfl_down(v, off);
  if ((t & 63) == 0) sred[wid] = v;
  __syncthreads();
  float mu = (sred[2*r] + sred[2*r+1]) * (1.f/128.f);
  float dx = x - mu;
  v = dx*dx;
  #pragma unroll
  for (int off = 32; off; off >>= 1) v += __shfl_down(v, off);
  if ((t & 63) == 0) sred[4 + wid] = v;
  __syncthreads();
  float var = (sred[4 + 2*r] + sred[4 + 2*r+1]) * (1.f/128.f);
  float y = dx * rsqrtf(var + 1e-5f);
  if (gr < NL) y = fmaf(y, g_l[c], be_l[c]);
  else         y = fmaf(y, g_p[c], be_p[c]);
  out[(size_t)gr*HDIM + c] = y;
}

extern "C" void kernel_launch(void* const* d_in, const int* in_sizes, int n_in,
                              void* d_out, int out_size, void* d_ws, size_t ws_size,
                              hipStream_t stream){
  const float* lf   = (const float*)d_in[0];
  const float* pf   = (const float*)d_in[1];
  const float* lc   = (const float*)d_in[2];
  const float* pc   = (const float*)d_in[3];
  const float* Wl   = (const float*)d_in[4];
  const float* bl   = (const float*)d_in[5];
  const float* Wp   = (const float*)d_in[6];
  const float* bp   = (const float*)d_in[7];
  const float* Wd1  = (const float*)d_in[8];
  const float* bd1  = (const float*)d_in[9];
  const float* Wd2  = (const float*)d_in[10];
  const float* bd2  = (const float*)d_in[11];
  const float* Wd3  = (const float*)d_in[12];
  const float* bd3  = (const float*)d_in[13];
  const float* Wgl  = (const float*)d_in[14];
  const float* bgl  = (const float*)d_in[15];
  const float* Wgp  = (const float*)d_in[16];
  const float* bgp  = (const float*)d_in[17];
  const float* Wqkv = (const float*)d_in[18];
  const float* bqkv = (const float*)d_in[19];
  const float* Wo   = (const float*)d_in[20];
  const float* bo   = (const float*)d_in[21];
  const float* g_l  = (const float*)d_in[22];
  const float* be_l = (const float*)d_in[23];
  const float* g_p  = (const float*)d_in[24];
  const float* be_p = (const float*)d_in[25];

  float* ws  = (float*)d_ws;
  float* out = (float*)d_out;

  void* args[] = { (void*)&lf, (void*)&pf, (void*)&lc, (void*)&pc,
                   (void*)&Wl, (void*)&bl, (void*)&Wp, (void*)&bp,
                   (void*)&Wd1, (void*)&bd1, (void*)&Wd2, (void*)&bd2,
                   (void*)&Wd3, (void*)&bd3, (void*)&Wgl, (void*)&bgl,
                   (void*)&Wgp, (void*)&bgp, (void*)&Wqkv, (void*)&bqkv,
                   (void*)&Wo, (void*)&bo, (void*)&g_l, (void*)&be_l,
                   (void*)&g_p, (void*)&be_p, (void*)&ws, (void*)&out };

  hipError_t err = hipLaunchCooperativeKernel((const void*)fused_all,
                                              dim3(512), dim3(512), args, 0, stream);
  if (err != hipSuccess){
    // Fallback: proven 5-kernel pipeline
    float* lig   = ws + LIG_OFF;
    float* poc   = ws + POC_OFF;
    float* lenh  = ws + LENH_OFF;
    float* penh  = ws + PENH_OFF;
    float* qkvl  = ws + QKVL_OFF;
    float* qkvp  = ws + QKVP_OFF;
    float* partL = ws + PARTL_OFF;
    float* partP = ws + PARTP_OFF;
    float* tab   = ws + TAB_OFF;

    prep_all<<<192, 256, 0, stream>>>(Wl, Wp, Wqkv, Wo, Wgl, Wgp, Wd1, bd1, Wd2, bd2, Wd3, bd3, ws);
    proj_kernel<<<NL/2 + NP/2, 256, 0, stream>>>(lf, pf, ws + WLT_OFF, bl, ws + WPT_OFF, bp, lig, poc);
    agg_gate_fused<<<NL/2 + NP/2, 512, 0, stream>>>(lc, pc, tab, lig, poc,
                                                    ws + WGLT_OFF, bgl, ws + WGPT_OFF, bgp,
                                                    ws + WQT_OFF, bqkv,
                                                    lenh, penh, qkvl, qkvp);
    attn_part<<<512, 256, 0, stream>>>(qkvl, qkvp, partL, partP);
    merge_ln<<<NL/2 + NP/2, 256, 0, stream>>>(partL, partP, lenh, penh, ws + WOT_OFF, bo,
                                              g_l, be_l, g_p, be_p, out);
  }
}

// Round 3
// 195.311 us; speedup vs baseline: 2.8974x; 2.8974x over previous
//
#include <hip/hip_runtime.h>
#include <hip/hip_cooperative_groups.h>
#include <math.h>

namespace cg = cooperative_groups;

#define NL 512
#define NP 1024
#define HDIM 128

#define TAB_N 8192
#define DMAX 34.65f

// ---- workspace layout (float offsets) ----
#define M_OFF    128
#define WLT_OFF  (M_OFF)                      // WlT  [128][128]
#define WPT_OFF  (M_OFF + 16384)              // WpT  [128][128]
#define WQT_OFF  (M_OFF + 32768)              // WqkvT[128][384]
#define WOT_OFF  (M_OFF + 81920)              // WoT  [128][128]
#define WGLT_OFF (M_OFF + 98304)              // WglT [256][128]
#define WGPT_OFF (M_OFF + 131072)             // WgpT [256][128]
#define TAB_OFF  (M_OFF + 163840)             // m(d) table
#define LIG_OFF  (M_OFF + NL*NP)              // lig proj 512x128
#define POC_OFF  (LIG_OFF + NL*HDIM)          // poc proj 1024x128
#define LENH_OFF (POC_OFF + NP*HDIM)          // lig_enh 512x128
#define PENH_OFF (LENH_OFF + NL*HDIM)         // poc_enh 1024x128
#define QKVL_OFF (PENH_OFF + NP*HDIM)         // qkv for lig_enh 512x384
#define QKVP_OFF (QKVL_OFF + NL*384)          // qkv for poc_enh 1024x384
#define PARTL_OFF (QKVP_OFF + NP*384)         // lig partials: [512][8 h][8 slices][18]
#define PARTP_OFF (PARTL_OFF + 512*8*8*18)    // poc partials: [1024][8 h][4 slices][18]

__device__ __forceinline__ float dot4f(float4 a, float4 b){
  return fmaf(a.x,b.x, fmaf(a.y,b.y, fmaf(a.z,b.z, a.w*b.w)));
}

// ---- P2a task: softmax over partners + aggregation for 2 rows, whole block (512 thr).
// PER = partners/256 (4 for lig rows, 2 for poc rows). Result (2x128) -> aggDst (LDS).
template<int PER>
__device__ __forceinline__ void agg_task(int t, int r0,
                                         const float* __restrict__ myC,
                                         const float* __restrict__ otC,
                                         const float* __restrict__ otherFeat,
                                         const float* __restrict__ tab,
                                         float* __restrict__ smem,
                                         float* __restrict__ aggDst)
{
  const int n = PER * 256;
  float*  w     = smem;                       // 2*n floats (max 2048)
  float4* part4 = (float4*)(smem + 4096);     // 512 float4 = 2048 floats
  float*  redm  = smem + 6144;                // 8
  float*  sgm   = smem + 6152;                // 2
  float*  sinv  = smem + 6154;                // 2

  int rr = t >> 8, u = t & 255;
  int lane = t & 63, wv = t >> 6;
  int row = r0 + rr;
  const float inv_h = (float)(TAB_N - 1) / DMAX;

  float cx = myC[row*3+0], cy = myC[row*3+1], cz = myC[row*3+2];

  float xs[PER];
  float lmax = -1e30f;
  #pragma unroll
  for (int k = 0; k < PER; k++){
    int j = u + (k << 8);
    float ox = otC[j*3+0], oy = otC[j*3+1], oz = otC[j*3+2];
    float dx = cx-ox, dy = cy-oy, dz = cz-oz;
    float d = sqrtf(fmaf(dx,dx, fmaf(dy,dy, dz*dz)));
    float xf = d * inv_h;
    int i0 = (int)xf;
    i0 = (i0 > TAB_N-2) ? (TAB_N-2) : i0;
    float f = xf - (float)i0;
    float v0 = tab[i0], v1 = tab[i0+1];
    xs[k] = -fmaf(f, v1 - v0, v0);
    lmax = fmaxf(lmax, xs[k]);
  }
  float v = lmax;
  #pragma unroll
  for (int off = 32; off; off >>= 1) v = fmaxf(v, __shfl_down(v, off));
  if (lane == 0) redm[wv] = v;
  __syncthreads();
  if (t < 2) sgm[t] = fmaxf(fmaxf(redm[t*4+0], redm[t*4+1]), fmaxf(redm[t*4+2], redm[t*4+3]));
  __syncthreads();
  float gm = sgm[rr];
  float lsum = 0.f;
  #pragma unroll
  for (int k = 0; k < PER; k++){
    float e = __expf(xs[k] - gm);
    w[rr*n + u + (k << 8)] = e;
    lsum += e;
  }
  v = lsum;
  #pragma unroll
  for (int off = 32; off; off >>= 1) v += __shfl_down(v, off);
  if (lane == 0) redm[wv] = v;
  __syncthreads();
  if (t < 2) sinv[t] = 1.0f / ((redm[t*4+0] + redm[t*4+1]) + (redm[t*4+2] + redm[t*4+3]));
  __syncthreads();

  // aggregation: 8 j-groups x 2 rows x 32 float4 cols
  {
    int jg = t >> 6;
    int r  = (t >> 5) & 1;
    int c4 = t & 31;
    const int per2 = n >> 3;                  // 128 or 64
    int jb0 = jg * per2;
    const float4* of4 = (const float4*)otherFeat;
    const float* wR = w + r*n;
    float4 acc = {0,0,0,0};
    #pragma unroll 4
    for (int jj = 0; jj < per2; jj++){
      int j = jb0 + jj;
      float4 f = of4[(size_t)j*32 + c4];
      float ww = wR[j];
      acc.x = fmaf(ww, f.x, acc.x); acc.y = fmaf(ww, f.y, acc.y);
      acc.z = fmaf(ww, f.z, acc.z); acc.w = fmaf(ww, f.w, acc.w);
    }
    part4[(jg*2 + r)*32 + c4] = acc;
  }
  __syncthreads();
  #pragma unroll
  for (int s2 = 4; s2 >= 1; s2 >>= 1){
    if (t < s2*64){
      int g2 = t >> 6, rem = t & 63;
      float4 a = part4[g2*64 + rem], bb = part4[(g2+s2)*64 + rem];
      a.x += bb.x; a.y += bb.y; a.z += bb.z; a.w += bb.w;
      part4[g2*64 + rem] = a;
    }
    __syncthreads();
  }
  if (t < 256) aggDst[t] = ((const float*)part4)[t] * sinv[t >> 7];
  __syncthreads();
}

// =====================================================================================
// Fused cooperative kernel: 256 blocks x 512 threads, 64 KB LDS, 1 block/CU.
// __launch_bounds__(512, 2): 2 waves/EU minimum -> VGPR cap 256 -> block ALWAYS
// schedulable (8 waves = 2/SIMD fit at <=256 VGPR) and 256 blocks always co-resident.
// (R1's (512,4) capped VGPR at 64 -> spills; R2's (512,1) allowed >256 VGPR -> the
// cooperative launch could become unschedulable and poison graph capture.)
// Phases: P0 transposes+LUT | P1 proj | P2 agg+gate+QKV (block-local handoff) | P3 attn | P4 merge+LN
// =====================================================================================
__global__ __launch_bounds__(512, 2) void fused_all(
  const float* __restrict__ lf, const float* __restrict__ pf,
  const float* __restrict__ lc, const float* __restrict__ pc,
  const float* __restrict__ Wl, const float* __restrict__ bl,
  const float* __restrict__ Wp, const float* __restrict__ bp,
  const float* __restrict__ Wd1, const float* __restrict__ bd1,
  const float* __restrict__ Wd2, const float* __restrict__ bd2,
  const float* __restrict__ Wd3, const float* __restrict__ bd3,
  const float* __restrict__ Wgl, const float* __restrict__ bgl,
  const float* __restrict__ Wgp, const float* __restrict__ bgp,
  const float* __restrict__ Wqkv, const float* __restrict__ bqkv,
  const float* __restrict__ Wo, const float* __restrict__ bo,
  const float* __restrict__ g_l, const float* __restrict__ be_l,
  const float* __restrict__ g_p, const float* __restrict__ be_p,
  float* __restrict__ ws, float* __restrict__ out)
{
  cg::grid_group grd = cg::this_grid();
  const int b = blockIdx.x;      // 0..255
  const int t = threadIdx.x;     // 0..511

  __shared__ __align__(16) float smem[16384];   // 64 KB

  float* WlT   = ws + WLT_OFF;
  float* WpT   = ws + WPT_OFF;
  float* WqkvT = ws + WQT_OFF;
  float* WoT   = ws + WOT_OFF;
  float* WglT  = ws + WGLT_OFF;
  float* WgpT  = ws + WGPT_OFF;
  float* tab   = ws + TAB_OFF;
  float* lig   = ws + LIG_OFF;
  float* poc   = ws + POC_OFF;
  float* lenh  = ws + LENH_OFF;
  float* penh  = ws + PENH_OFF;
  float* qkvl  = ws + QKVL_OFF;
  float* qkvp  = ws + QKVP_OFF;
  float* partL = ws + PARTL_OFF;
  float* partP = ws + PARTP_OFF;

  // ---------------- P0: ALL weight transposes + m(d) LUT ----------------
  {
    int e = b*512 + t;                   // 0..131071
    if (e < 16384){
      int o = e >> 7, k = e & 127;
      WlT[k*128 + o] = Wl[e];
    } else if (e < 32768){
      int loc = e - 16384, o = loc >> 7, k = loc & 127;
      WpT[k*128 + o] = Wp[loc];
    }
    // remaining transpose elements (overlapped ranges; e<32768 threads do double duty)
    if (e < 49152){                       // Wqkv [384][128]
      int o = e >> 7, k = e & 127;
      WqkvT[k*384 + o] = Wqkv[e];
    } else if (e < 65536){                // Wo [128][128]
      int loc = e - 49152, o = loc >> 7, k = loc & 127;
      WoT[k*128 + o] = Wo[loc];
    } else if (e < 98304){                // Wgl [128][256]
      int loc = e - 65536, o = loc >> 8, k = loc & 255;
      WglT[k*128 + o] = Wgl[loc];
    } else {                              // Wgp [128][256]
      int loc = e - 98304, o = loc >> 8, k = loc & 255;
      WgpT[k*128 + o] = Wgp[loc];
    }

    if (b >= 240){
      // LUT: blocks 240..255, 512 entries each
      float* sWd1  = smem;          // 32
      float* sbd1  = smem + 32;     // 32
      float* sbd2  = smem + 64;     // 64
      float* swd3m = smem + 128;    // 64
      float* sWd2  = smem + 256;    // 2048
      if (t < 64){
        float ssum = 0.f;
        #pragma unroll 8
        for (int i = 0; i < 128; i++) ssum += Wd3[i*64 + t];
        swd3m[t] = ssum * (1.f/128.f);
      } else if (t == 64){
        float ssum = 0.f;
        for (int i = 0; i < 128; i++) ssum += bd3[i];
        smem[192] = ssum * (1.f/128.f);
      } else if (t >= 128 && t < 160){ sWd1[t-128] = Wd1[t-128]; sbd1[t-128] = bd1[t-128]; }
      else if (t >= 160 && t < 224){ sbd2[t-160] = bd2[t-160]; }
      for (int k = t; k < 2048; k += 512) sWd2[k] = Wd2[k];
      __syncthreads();

      int idx = (b - 240)*512 + t;
      float d = (float)idx * (DMAX / (float)(TAB_N - 1));
      float4 e1q[8];
      const float4* w1q = (const float4*)sWd1;
      const float4* b1q = (const float4*)sbd1;
      #pragma unroll
      for (int k4 = 0; k4 < 8; k4++){
        float4 w = w1q[k4], bb = b1q[k4];
        float4 ev;
        ev.x = fmaxf(fmaf(d, w.x, bb.x), 0.f);
        ev.y = fmaxf(fmaf(d, w.y, bb.y), 0.f);
        ev.z = fmaxf(fmaf(d, w.z, bb.z), 0.f);
        ev.w = fmaxf(fmaf(d, w.w, bb.w), 0.f);
        e1q[k4] = ev;
      }
      float mv = smem[192];
      #pragma unroll 4
      for (int j2 = 0; j2 < 64; j2++){
        const float4* wrow = (const float4*)(sWd2 + j2*32);
        float a0 = 0.f, a1 = 0.f, a2 = 0.f, a3 = 0.f;
        #pragma unroll
        for (int k4 = 0; k4 < 8; k4++){
          float4 w = wrow[k4], ev = e1q[k4];
          a0 = fmaf(w.x, ev.x, a0);
          a1 = fmaf(w.y, ev.y, a1);
          a2 = fmaf(w.z, ev.z, a2);
          a3 = fmaf(w.w, ev.w, a3);
        }
        float e2v = fmaxf(sbd2[j2] + ((a0+a1)+(a2+a3)), 0.f);
        mv = fmaf(swd3m[j2], e2v, mv);
      }
      tab[idx] = mv;
    }
  }
  grd.sync();

  // ---------------- P1: input projections (768 row-pair tasks) ----------------
  {
    int sub = t >> 8, st = t & 255;
    int nit = (b < 128) ? 2 : 1;
    for (int it = 0; it < nit; it++){
      int s = b*2 + sub + it*512;           // 0..767
      bool isLig = (s < 256);
      int r0 = isLig ? s*2 : (s - 256)*2;
      const float* in  = (isLig ? lf : pf) + (size_t)r0*HDIM;
      const float* WT  = isLig ? WlT : WpT;
      const float* bia = isLig ? bl : bp;
      float* o = (isLig ? lig : poc) + (size_t)r0*HDIM;
      float* sx = smem + sub*256;
      __syncthreads();
      sx[st] = in[st];
      __syncthreads();
      int r = st >> 7, col = st & 127;
      const float* xr = sx + r*HDIM;
      float acc = bia[col];
      #pragma unroll 8
      for (int k = 0; k < 128; k++) acc = fmaf(WT[k*128 + col], xr[k], acc);
      o[r*HDIM + col] = acc;
    }
  }
  grd.sync();

  // ---------------- P2: agg (block-local) + gate + QKV ----------------
  // Block b owns lig rows {2b,2b+1} and poc rows {4b..4b+3}; agg rows stay in LDS.
  {
    float* AGG = smem + 14336;                // 6 rows x 128 = 768 floats
    agg_task<4>(t, 2*b,     lc, pc, poc, tab, smem, AGG);        // lig pair
    agg_task<2>(t, 4*b,     pc, lc, lig, tab, smem, AGG + 256);  // poc pair 0
    agg_task<2>(t, 4*b + 2, pc, lc, lig, tab, smem, AGG + 512);  // poc pair 1

    float* sx    = smem;          // 128
    float* se    = smem + 128;    // 128
    float* gpart = smem + 256;    // 512
    for (int i = 0; i < 6; i++){
      bool isLig = (i < 2);
      int row = isLig ? (2*b + i) : (4*b + (i - 2));
      const float* xsrc = (isLig ? lig : poc) + (size_t)row*HDIM;
      const float* arow = AGG + i*128;
      __syncthreads();
      if (t < 128) sx[t] = xsrc[t];
      __syncthreads();
      {
        int col = t & 127, kg = t >> 7;       // kg 0..3: k-quarter
        const float* WT = isLig ? WglT : WgpT;
        const float* inb = (kg < 2) ? sx : (arow - 128);
        int k0 = kg*64;
        float acc = 0.f;
        #pragma unroll 8
        for (int kk = 0; kk < 64; kk++){
          int k = k0 + kk;
          acc = fmaf(WT[(size_t)k*128 + col], inb[k], acc);
        }
        gpart[kg*128 + col] = acc;
      }
      __syncthreads();
      if (t < 128){
        const float* bg = isLig ? bgl : bgp;
        float g = bg[t] + ((gpart[t] + gpart[128+t]) + (gpart[256+t] + gpart[384+t]));
        g = 1.0f / (1.0f + __expf(-g));
        float xv = sx[t], av = arow[t];
        float enh = fmaf(g, xv - av, av);     // g*x + (1-g)*a
        se[t] = enh;
        float* dst = isLig ? (lenh + (size_t)row*HDIM) : (penh + (size_t)row*HDIM);
        dst[t] = enh;
      }
      __syncthreads();
      if (t < 384){
        float acc = bqkv[t];
        #pragma unroll 8
        for (int k = 0; k < 128; k++) acc = fmaf(WqkvT[(size_t)k*384 + t], se[k], acc);
        float* q = (isLig ? qkvl : qkvp) + (size_t)row*384;
        q[t] = acc;
      }
    }
  }
  grd.sync();

  // ---------------- P3: flash attention, 2 tasks/block, 8 split-k groups x 16 keys ----------------
  // KV LDS chunk swizzle: chunk c -> (c & ~3) | ((c&3) ^ ((c>>2)&3)); cuts 4-way bank conflict to 2-way (free).
  {
    for (int it = 0; it < 2; it++){
      const float* qsrc; const float* kvsrc; int qt, slice; bool isLig;
      if (it == 0){ isLig = true;  qt = b >> 3; slice = b & 7; qsrc = qkvl; kvsrc = qkvp; }
      else        { isLig = false; qt = b >> 2; slice = b & 3; qsrc = qkvp; kvsrc = qkvl; }
      int g = t >> 6, tt = t & 63;
      int h = tt >> 3, qp = tt & 7;
      int j0 = slice*128 + g*16;
      int hx = h & 3;

      const float4* qA = (const float4*)(qsrc + (size_t)(qt*16+qp)*384 + h*16);
      const float4* qB = (const float4*)(qsrc + (size_t)(qt*16+qp+8)*384 + h*16);
      float4 a0 = qA[0], a1 = qA[1], a2 = qA[2], a3 = qA[3];
      float4 b0 = qB[0], b1 = qB[1], b2 = qB[2], b3 = qB[3];
      float mA = -1e30f, lA = 0.f, mB = -1e30f, lB = 0.f;
      float4 OA0={0,0,0,0}, OA1={0,0,0,0}, OA2={0,0,0,0}, OA3={0,0,0,0};
      float4 OB0={0,0,0,0}, OB1={0,0,0,0}, OB2={0,0,0,0}, OB3={0,0,0,0};

      float* myKV = smem + g*2048;               // 8 keys x 256 floats

      for (int tile = 0; tile < 2; tile++){
        int jbase = j0 + tile*8;
        __syncthreads();
        #pragma unroll
        for (int nn = 0; nn < 8; nn++){
          int v4 = tt + nn*64;
          int jj = v4 >> 6, c4 = v4 & 63;
          int c4s = (c4 & 60) | ((c4 ^ (c4 >> 2)) & 3);
          ((float4*)myKV)[jj*64 + c4s] = *(const float4*)(kvsrc + (size_t)(jbase+jj)*384 + 128 + c4*4);
        }
        __syncthreads();
        float sA[8], sB[8];
        #pragma unroll
        for (int jj = 0; jj < 8; jj++){
          const float4* kb = ((const float4*)myKV) + jj*64 + h*4;
          float4 k0 = kb[0^hx], k1 = kb[1^hx], k2 = kb[2^hx], k3 = kb[3^hx];
          sA[jj] = (dot4f(a0,k0) + dot4f(a1,k1) + dot4f(a2,k2) + dot4f(a3,k3)) * 0.25f;
          sB[jj] = (dot4f(b0,k0) + dot4f(b1,k1) + dot4f(b2,k2) + dot4f(b3,k3)) * 0.25f;
        }
        float mtA = sA[0], mtB = sB[0];
        #pragma unroll
        for (int jj = 1; jj < 8; jj++){ mtA = fmaxf(mtA, sA[jj]); mtB = fmaxf(mtB, sB[jj]); }
        float mnA = fmaxf(mA, mtA), mnB = fmaxf(mB, mtB);
        float cA = __expf(mA - mnA), cB = __expf(mB - mnB);
        lA *= cA; lB *= cB;
        OA0.x*=cA; OA0.y*=cA; OA0.z*=cA; OA0.w*=cA;
        OA1.x*=cA; OA1.y*=cA; OA1.z*=cA; OA1.w*=cA;
        OA2.x*=cA; OA2.y*=cA; OA2.z*=cA; OA2.w*=cA;
        OA3.x*=cA; OA3.y*=cA; OA3.z*=cA; OA3.w*=cA;
        OB0.x*=cB; OB0.y*=cB; OB0.z*=cB; OB0.w*=cB;
        OB1.x*=cB; OB1.y*=cB; OB1.z*=cB; OB1.w*=cB;
        OB2.x*=cB; OB2.y*=cB; OB2.z*=cB; OB2.w*=cB;
        OB3.x*=cB; OB3.y*=cB; OB3.z*=cB; OB3.w*=cB;
        #pragma unroll
        for (int jj = 0; jj < 8; jj++){
          float pA = __expf(sA[jj] - mnA);
          float pB = __expf(sB[jj] - mnB);
          lA += pA; lB += pB;
          const float4* vb = ((const float4*)myKV) + jj*64 + 32 + h*4;
          float4 v0 = vb[0^hx], v1 = vb[1^hx], v2 = vb[2^hx], v3 = vb[3^hx];
          OA0.x = fmaf(pA, v0.x, OA0.x); OA0.y = fmaf(pA, v0.y, OA0.y);
          OA0.z = fmaf(pA, v0.z, OA0.z); OA0.w = fmaf(pA, v0.w, OA0.w);
          OA1.x = fmaf(pA, v1.x, OA1.x); OA1.y = fmaf(pA, v1.y, OA1.y);
          OA1.z = fmaf(pA, v1.z, OA1.z); OA1.w = fmaf(pA, v1.w, OA1.w);
          OA2.x = fmaf(pA, v2.x, OA2.x); OA2.y = fmaf(pA, v2.y, OA2.y);
          OA2.z = fmaf(pA, v2.z, OA2.z); OA2.w = fmaf(pA, v2.w, OA2.w);
          OA3.x = fmaf(pA, v3.x, OA3.x); OA3.y = fmaf(pA, v3.y, OA3.y);
          OA3.z = fmaf(pA, v3.z, OA3.z); OA3.w = fmaf(pA, v3.w, OA3.w);
          OB0.x = fmaf(pB, v0.x, OB0.x); OB0.y = fmaf(pB, v0.y, OB0.y);
          OB0.z = fmaf(pB, v0.z, OB0.z); OB0.w = fmaf(pB, v0.w, OB0.w);
          OB1.x = fmaf(pB, v1.x, OB1.x); OB1.y = fmaf(pB, v1.y, OB1.y);
          OB1.z = fmaf(pB, v1.z, OB1.z); OB1.w = fmaf(pB, v1.w, OB1.w);
          OB2.x = fmaf(pB, v2.x, OB2.x); OB2.y = fmaf(pB, v2.y, OB2.y);
          OB2.z = fmaf(pB, v2.z, OB2.z); OB2.w = fmaf(pB, v2.w, OB2.w);
          OB3.x = fmaf(pB, v3.x, OB3.x); OB3.y = fmaf(pB, v3.y, OB3.y);
          OB3.z = fmaf(pB, v3.z, OB3.z); OB3.w = fmaf(pB, v3.w, OB3.w);
        }
        mA = mnA; mB = mnB;
      }

      // merge 8 split-k groups via LDS (groups 1..7 publish; group 0 merges)
      __syncthreads();
      if (g > 0){
        float* bA = smem + (size_t)((g-1)*128 + tt*2)*18;
        bA[0]=mA; bA[1]=lA;
        bA[2]=OA0.x; bA[3]=OA0.y; bA[4]=OA0.z; bA[5]=OA0.w;
        bA[6]=OA1.x; bA[7]=OA1.y; bA[8]=OA1.z; bA[9]=OA1.w;
        bA[10]=OA2.x; bA[11]=OA2.y; bA[12]=OA2.z; bA[13]=OA2.w;
        bA[14]=OA3.x; bA[15]=OA3.y; bA[16]=OA3.z; bA[17]=OA3.w;
        float* bB = bA + 18;
        bB[0]=mB; bB[1]=lB;
        bB[2]=OB0.x; bB[3]=OB0.y; bB[4]=OB0.z; bB[5]=OB0.w;
        bB[6]=OB1.x; bB[7]=OB1.y; bB[8]=OB1.z; bB[9]=OB1.w;
        bB[10]=OB2.x; bB[11]=OB2.y; bB[12]=OB2.z; bB[13]=OB2.w;
        bB[14]=OB3.x; bB[15]=OB3.y; bB[16]=OB3.z; bB[17]=OB3.w;
      }
      __syncthreads();
      if (g == 0){
        float M = mA, L = lA;
        float O[16] = {OA0.x,OA0.y,OA0.z,OA0.w, OA1.x,OA1.y,OA1.z,OA1.w,
                       OA2.x,OA2.y,OA2.z,OA2.w, OA3.x,OA3.y,OA3.z,OA3.w};
        #pragma unroll
        for (int gg = 1; gg < 8; gg++){
          const float* br = smem + (size_t)((gg-1)*128 + tt*2)*18;
          float m1 = br[0], l1 = br[1];
          float Mn = fmaxf(M, m1);
          float e0 = __expf(M - Mn), e1 = __expf(m1 - Mn);
          L = L*e0 + l1*e1;
          #pragma unroll
          for (int k = 0; k < 16; k++) O[k] = O[k]*e0 + br[2+k]*e1;
          M = Mn;
        }
        int rowA = qt*16 + qp;
        float* dst = isLig ? (partL + ((size_t)(rowA*8 + h)*8 + slice)*18)
                           : (partP + ((size_t)(rowA*8 + h)*4 + slice)*18);
        dst[0] = M; dst[1] = L;
        #pragma unroll
        for (int k = 0; k < 16; k++) dst[2+k] = O[k];
        M = mB; L = lB;
        float Ob[16] = {OB0.x,OB0.y,OB0.z,OB0.w, OB1.x,OB1.y,OB1.z,OB1.w,
                        OB2.x,OB2.y,OB2.z,OB2.w, OB3.x,OB3.y,OB3.z,OB3.w};
        #pragma unroll
        for (int gg = 1; gg < 8; gg++){
          const float* br = smem + (size_t)((gg-1)*128 + tt*2)*18 + 18;
          float m1 = br[0], l1 = br[1];
          float Mn = fmaxf(M, m1);
          float e0 = __expf(M - Mn), e1 = __expf(m1 - Mn);
          L = L*e0 + l1*e1;
          #pragma unroll
          for (int k = 0; k < 16; k++) Ob[k] = Ob[k]*e0 + br[2+k]*e1;
          M = Mn;
        }
        int rowB = qt*16 + qp + 8;
        float* dstB = isLig ? (partL + ((size_t)(rowB*8 + h)*8 + slice)*18)
                            : (partP + ((size_t)(rowB*8 + h)*4 + slice)*18);
        dstB[0] = M; dstB[1] = L;
        #pragma unroll
        for (int k = 0; k < 16; k++) dstB[2+k] = Ob[k];
      }
    }
  }
  grd.sync();

  // ---------------- P4: merge partials + Wo proj + residual + LayerNorm (768 row-pair tasks) ----------------
  {
    int sub = t >> 8, st = t & 255;
    int nit = (b < 128) ? 2 : 1;
    for (int it = 0; it < nit; it++){
      int s = b*2 + sub + it*512;            // 0..767
      int r0 = s*2;
      int r = st >> 7, c = st & 127;
      int gr = r0 + r;
      int hh = c >> 4, cc = c & 15;
      int ns; const float* base;
      if (gr < NL){ ns = 8; base = partL + ((size_t)(gr*8 + hh))*8*18; }
      else        { ns = 4; base = partP + ((size_t)((gr-NL)*8 + hh))*4*18; }
      float M = -1e30f;
      for (int sl = 0; sl < ns; sl++) M = fmaxf(M, base[sl*18]);
      float Lsum = 0.f, Osum = 0.f;
      for (int sl = 0; sl < ns; sl++){
        float e = __expf(base[sl*18] - M);
        Lsum = fmaf(e, base[sl*18+1], Lsum);
        Osum = fmaf(e, base[sl*18+2+cc], Osum);
      }
      float* sAtt = smem + sub*256;
      float* sred = smem + 512 + sub*16;
      __syncthreads();
      sAtt[st] = Osum / Lsum;
      __syncthreads();
      float o = bo[c];
      const float* sA = sAtt + r*HDIM;
      #pragma unroll 8
      for (int k = 0; k < 128; k++) o = fmaf(WoT[k*128 + c], sA[k], o);
      const float* enh = (gr < NL) ? (lenh + (size_t)gr*HDIM) : (penh + (size_t)(gr-NL)*HDIM);
      float x = enh[c] + o;
      int wid = st >> 6;
      float v = x;
      #pragma unroll
      for (int off = 32; off; off >>= 1) v += __shfl_down(v, off);
      if ((st & 63) == 0) sred[wid] = v;
      __syncthreads();
      float mu = (sred[2*r] + sred[2*r+1]) * (1.f/128.f);
      float dx = x - mu;
      v = dx*dx;
      #pragma unroll
      for (int off = 32; off; off >>= 1) v += __shfl_down(v, off);
      if ((st & 63) == 0) sred[4 + wid] = v;
      __syncthreads();
      float var = (sred[4 + 2*r] + sred[4 + 2*r+1]) * (1.f/128.f);
      float y = dx * rsqrtf(var + 1e-5f);
      if (gr < NL) y = fmaf(y, g_l[c], be_l[c]);
      else         y = fmaf(y, g_p[c], be_p[c]);
      out[(size_t)gr*HDIM + c] = y;
    }
  }
}

// =====================================================================================
// Fallback path: the proven 5-kernel pipeline (used only if coop occupancy check fails)
// =====================================================================================
__device__ __forceinline__ void tpose(const float* __restrict__ src, float* __restrict__ dst,
                                      int O, int K, int blk0, int t){
  int e0 = blk0*1024 + t*4;
  #pragma unroll
  for (int i = 0; i < 4; i++){
    int e = e0 + i;
    int o = e / K, k = e - o*K;
    dst[(size_t)k*O + o] = src[(size_t)o*K + k];
  }
}
__global__ __launch_bounds__(256) void prep_all(const float* __restrict__ Wl, const float* __restrict__ Wp,
                                                const float* __restrict__ Wqkv, const float* __restrict__ Wo,
                                                const float* __restrict__ Wgl, const float* __restrict__ Wgp,
                                                const float* __restrict__ Wd1, const float* __restrict__ bd1,
                                                const float* __restrict__ Wd2, const float* __restrict__ bd2,
                                                const float* __restrict__ Wd3, const float* __restrict__ bd3,
                                                float* __restrict__ ws){
  int b = blockIdx.x, t = threadIdx.x;
  if (b < 160){
    if      (b < 16)  tpose(Wl,   ws + WLT_OFF,  128, 128, b,       t);
    else if (b < 32)  tpose(Wp,   ws + WPT_OFF,  128, 128, b - 16,  t);
    else if (b < 80)  tpose(Wqkv, ws + WQT_OFF,  384, 128, b - 32,  t);
    else if (b < 96)  tpose(Wo,   ws + WOT_OFF,  128, 128, b - 80,  t);
    else if (b < 128) tpose(Wgl,  ws + WGLT_OFF, 128, 256, b - 96,  t);
    else              tpose(Wgp,  ws + WGPT_OFF, 128, 256, b - 128, t);
    return;
  }
  float* tab = ws + TAB_OFF;
  __shared__ float sWd1[32], sbd1[32], sWd2[2048], sbd2[64], swd3m[64];
  __shared__ float sbd3m;
  int idx = (b - 160) * 256 + t;
  if (t < 64){
    float s = 0.f;
    #pragma unroll 8
    for (int i = 0; i < 128; i++) s += Wd3[i*64 + t];
    swd3m[t] = s * (1.f/128.f);
  } else if (t == 64){
    float s = 0.f;
    for (int i = 0; i < 128; i++) s += bd3[i];
    sbd3m = s * (1.f/128.f);
  } else if (t >= 128 && t < 160){ sWd1[t-128] = Wd1[t-128]; sbd1[t-128] = bd1[t-128]; }
  else if (t >= 160 && t < 224){ sbd2[t-160] = bd2[t-160]; }
  for (int k = t; k < 2048; k += 256) sWd2[k] = Wd2[k];
  __syncthreads();

  float d = (float)idx * (DMAX / (float)(TAB_N - 1));
  float4 e1q[8];
  const float4* w1q = (const float4*)sWd1;
  const float4* b1q = (const float4*)sbd1;
  #pragma unroll
  for (int k4 = 0; k4 < 8; k4++){
    float4 w = w1q[k4], bb = b1q[k4];
    float4 e;
    e.x = fmaxf(fmaf(d, w.x, bb.x), 0.f);
    e.y = fmaxf(fmaf(d, w.y, bb.y), 0.f);
    e.z = fmaxf(fmaf(d, w.z, bb.z), 0.f);
    e.w = fmaxf(fmaf(d, w.w, bb.w), 0.f);
    e1q[k4] = e;
  }
  float mv = sbd3m;
  #pragma unroll 4
  for (int j2 = 0; j2 < 64; j2++){
    const float4* wrow = (const float4*)(sWd2 + j2*32);
    float a0 = 0.f, a1 = 0.f, a2 = 0.f, a3 = 0.f;
    #pragma unroll
    for (int k4 = 0; k4 < 8; k4++){
      float4 w = wrow[k4], e = e1q[k4];
      a0 = fmaf(w.x, e.x, a0);
      a1 = fmaf(w.y, e.y, a1);
      a2 = fmaf(w.z, e.z, a2);
      a3 = fmaf(w.w, e.w, a3);
    }
    float e2v = fmaxf(sbd2[j2] + ((a0+a1)+(a2+a3)), 0.f);
    mv = fmaf(swd3m[j2], e2v, mv);
  }
  tab[idx] = mv;
}

__global__ __launch_bounds__(256) void proj_kernel(const float* __restrict__ lf, const float* __restrict__ pf,
                                                   const float* __restrict__ WlT, const float* __restrict__ bl,
                                                   const float* __restrict__ WpT, const float* __restrict__ bp,
                                                   float* __restrict__ lig, float* __restrict__ poc){
  int b = blockIdx.x, t = threadIdx.x;
  bool isLig = (b < NL/2);
  int r0 = isLig ? b*2 : (b - NL/2)*2;
  const float* in = (isLig ? lf : pf) + (size_t)r0*HDIM;
  const float* WT = isLig ? WlT : WpT;
  const float* bias = isLig ? bl : bp;
  float* out = (isLig ? lig : poc) + (size_t)r0*HDIM;
  __shared__ float sx[2*HDIM];
  sx[t] = in[t];
  __syncthreads();
  int r = t >> 7, col = t & 127;
  const float* xr = sx + r*HDIM;
  float acc = bias[col];
  #pragma unroll 8
  for (int k = 0; k < 128; k++) acc = fmaf(WT[k*128 + col], xr[k], acc);
  out[r*HDIM + col] = acc;
}

__global__ __launch_bounds__(512) void agg_gate_fused(const float* __restrict__ lc, const float* __restrict__ pc,
                                                      const float* __restrict__ tab,
                                                      const float* __restrict__ lig, const float* __restrict__ poc,
                                                      const float* __restrict__ WglT, const float* __restrict__ bgl,
                                                      const float* __restrict__ WgpT, const float* __restrict__ bgp,
                                                      const float* __restrict__ WqkvT, const float* __restrict__ bqkv,
                                                      float* __restrict__ lenh, float* __restrict__ penh,
                                                      float* __restrict__ qkvl, float* __restrict__ qkvp){
  int b = blockIdx.x, t = threadIdx.x;
  bool isLig = (b < NL/2);
  int r0 = isLig ? b*2 : (b - NL/2)*2;
  int n = isLig ? NP : NL;
  const float* myFeat = isLig ? lig : poc;
  const float* otherFeat = isLig ? poc : lig;
  const float* myC = isLig ? lc : pc;
  const float* otC = isLig ? pc : lc;

  __shared__ float w[2*NP];
  __shared__ float sx[2*HDIM];
  __shared__ float sa[2*HDIM];
  __shared__ float4 part4[8*64];
  __shared__ float gpart[512];
  __shared__ float redm[8];
  __shared__ float sgm[2], sinv[2];

  int rr = t >> 8, u = t & 255;
  int lane = t & 63, wv = t >> 6;
  int row = r0 + rr;

  if (t < 256) sx[t] = myFeat[(size_t)r0*HDIM + t];

  float cx = myC[row*3+0], cy = myC[row*3+1], cz = myC[row*3+2];
  const float inv_h = (float)(TAB_N - 1) / DMAX;
  int per = n >> 8;

  float xs[4];
  float lmax = -1e30f;
  for (int k = 0; k < per; k++){
    int j = u + (k << 8);
    float ox = otC[j*3+0], oy = otC[j*3+1], oz = otC[j*3+2];
    float dx = cx-ox, dy = cy-oy, dz = cz-oz;
    float d = sqrtf(fmaf(dx,dx, fmaf(dy,dy, dz*dz)));
    float xf = d * inv_h;
    int i0 = (int)xf;
    i0 = (i0 > TAB_N-2) ? (TAB_N-2) : i0;
    float f = xf - (float)i0;
    float v0 = tab[i0], v1 = tab[i0+1];
    xs[k] = -fmaf(f, v1 - v0, v0);
    lmax = fmaxf(lmax, xs[k]);
  }
  float v = lmax;
  #pragma unroll
  for (int off = 32; off; off >>= 1) v = fmaxf(v, __shfl_down(v, off));
  if (lane == 0) redm[wv] = v;
  __syncthreads();
  if (t < 2) sgm[t] = fmaxf(fmaxf(redm[t*4+0], redm[t*4+1]), fmaxf(redm[t*4+2], redm[t*4+3]));
  __syncthreads();
  float gm = sgm[rr];
  float lsum = 0.f;
  for (int k = 0; k < per; k++){
    float e = __expf(xs[k] - gm);
    w[rr*NP + u + (k << 8)] = e;
    lsum += e;
  }
  v = lsum;
  #pragma unroll
  for (int off = 32; off; off >>= 1) v += __shfl_down(v, off);
  if (lane == 0) redm[wv] = v;
  __syncthreads();
  if (t < 2) sinv[t] = 1.0f / ((redm[t*4+0] + redm[t*4+1]) + (redm[t*4+2] + redm[t*4+3]));
  __syncthreads();

  {
    int jg = t >> 6;
    int r  = (t >> 5) & 1;
    int c4 = t & 31;
    int per2 = n >> 3;
    int jb0 = jg * per2;
    const float4* of4 = (const float4*)otherFeat;
    const float* wR = w + r*NP;
    float4 acc = {0,0,0,0};
    #pragma unroll 4
    for (int jj = 0; jj < per2; jj++){
      int j = jb0 + jj;
      float4 f = of4[(size_t)j*32 + c4];
      float ww = wR[j];
      acc.x = fmaf(ww, f.x, acc.x); acc.y = fmaf(ww, f.y, acc.y);
      acc.z = fmaf(ww, f.z, acc.z); acc.w = fmaf(ww, f.w, acc.w);
    }
    part4[(jg*2 + r)*32 + c4] = acc;
  }
  __syncthreads();
  #pragma unroll
  for (int s = 4; s >= 1; s >>= 1){
    if (t < s*64){
      int g2 = t >> 6, rem = t & 63;
      float4 a = part4[g2*64 + rem], bb = part4[(g2+s)*64 + rem];
      a.x += bb.x; a.y += bb.y; a.z += bb.z; a.w += bb.w;
      part4[g2*64 + rem] = a;
    }
    __syncthreads();
  }
  if (t < 256) sa[t] = ((const float*)part4)[t] * sinv[t >> 7];
  __syncthreads();

  {
    int r  = t >> 8;
    int kg = (t >> 7) & 1;
    int col = t & 127;
    const float* WT = isLig ? WglT : WgpT;
    const float* inq = (kg == 0) ? (sx + r*HDIM) : (sa + r*HDIM);
    const float* wbase = WT + (size_t)kg*128*128;
    float g = 0.f;
    #pragma unroll 8
    for (int k = 0; k < 128; k++) g = fmaf(wbase[k*128 + col], inq[k], g);
    gpart[kg*256 + r*128 + col] = g;
  }
  __syncthreads();
  float enh_val = 0.f;
  if (t < 256){
    int r = t >> 7, col = t & 127;
    const float* bg = isLig ? bgl : bgp;
    float g = bg[col] + gpart[t] + gpart[256 + t];
    g = 1.0f / (1.0f + __expf(-g));
    float xv = sx[t], av = sa[t];
    enh_val = fmaf(g, xv - av, av);
    float* dst = isLig ? (lenh + (size_t)(r0+r)*HDIM) : (penh + (size_t)(r0+r)*HDIM);
    dst[col] = enh_val;
  }
  __syncthreads();
  if (t < 256) sa[t] = enh_val;
  __syncthreads();

  {
    int r = t >> 8, ln = t & 255;
    const float* er = sa + r*HDIM;
    float* qout = (isLig ? qkvl : qkvp) + (size_t)(r0+r)*384;
    if (ln < 128){
      float a0 = bqkv[ln], a2 = bqkv[ln+256];
      #pragma unroll 4
      for (int k = 0; k < 128; k++){
        float xv = er[k];
        const float* wk = WqkvT + k*384;
        a0 = fmaf(wk[ln],     xv, a0);
        a2 = fmaf(wk[ln+256], xv, a2);
      }
      qout[ln] = a0; qout[ln+256] = a2;
    } else {
      float a1 = bqkv[ln];
      #pragma unroll 4
      for (int k = 0; k < 128; k++) a1 = fmaf(WqkvT[k*384 + ln], er[k], a1);
      qout[ln] = a1;
    }
  }
}

__global__ __launch_bounds__(256) void attn_part(const float* __restrict__ qkvl, const float* __restrict__ qkvp,
                                                 float* __restrict__ partL, float* __restrict__ partP){
  int bx = blockIdx.x;
  int t = threadIdx.x;
  const float* qsrc; const float* kvsrc; int qt, slice; bool isLig;
  if (bx < 256){ isLig = true;  qt = bx >> 3; slice = bx & 7; qsrc = qkvl; kvsrc = qkvp; }
  else { int b2 = bx - 256; isLig = false; qt = b2 >> 2; slice = b2 & 3; qsrc = qkvp; kvsrc = qkvl; }
  int g = t >> 6, tt = t & 63;
  int h = tt >> 3, qp = tt & 7;
  int j0 = slice*128 + g*32;

  const float4* qA = (const float4*)(qsrc + (size_t)(qt*16+qp)*384 + h*16);
  const float4* qB = (const float4*)(qsrc + (size_t)(qt*16+qp+8)*384 + h*16);
  float4 a0 = qA[0], a1 = qA[1], a2 = qA[2], a3 = qA[3];
  float4 b0 = qB[0], b1 = qB[1], b2 = qB[2], b3 = qB[3];
  float mA = -1e30f, lA = 0.f, mB = -1e30f, lB = 0.f;
  float4 OA0={0,0,0,0}, OA1={0,0,0,0}, OA2={0,0,0,0}, OA3={0,0,0,0};
  float4 OB0={0,0,0,0}, OB1={0,0,0,0}, OB2={0,0,0,0}, OB3={0,0,0,0};

  __shared__ float sKV[8192];
  float* myKV = sKV + g*2048;

  for (int tile = 0; tile < 4; tile++){
    int jbase = j0 + tile*8;
    __syncthreads();
    #pragma unroll
    for (int nn = 0; nn < 8; nn++){
      int v4 = tt + nn*64;
      int jj = v4 >> 6, c4 = v4 & 63;
      ((float4*)myKV)[jj*64 + c4] = *(const float4*)(kvsrc + (size_t)(jbase+jj)*384 + 128 + c4*4);
    }
    __syncthreads();
    float sA[8], sB[8];
    #pragma unroll
    for (int jj = 0; jj < 8; jj++){
      const float4* kk = (const float4*)(myKV + jj*256 + h*16);
      float4 k0 = kk[0], k1 = kk[1], k2 = kk[2], k3 = kk[3];
      sA[jj] = (dot4f(a0,k0) + dot4f(a1,k1) + dot4f(a2,k2) + dot4f(a3,k3)) * 0.25f;
      sB[jj] = (dot4f(b0,k0) + dot4f(b1,k1) + dot4f(b2,k2) + dot4f(b3,k3)) * 0.25f;
    }
    float mtA = sA[0], mtB = sB[0];
    #pragma unroll
    for (int jj = 1; jj < 8; jj++){ mtA = fmaxf(mtA, sA[jj]); mtB = fmaxf(mtB, sB[jj]); }
    float mnA = fmaxf(mA, mtA), mnB = fmaxf(mB, mtB);
    float cA = __expf(mA - mnA), cB = __expf(mB - mnB);
    lA *= cA; lB *= cB;
    OA0.x*=cA; OA0.y*=cA; OA0.z*=cA; OA0.w*=cA;
    OA1.x*=cA; OA1.y*=cA; OA1.z*=cA; OA1.w*=cA;
    OA2.x*=cA; OA2.y*=cA; OA2.z*=cA; OA2.w*=cA;
    OA3.x*=cA; OA3.y*=cA; OA3.z*=cA; OA3.w*=cA;
    OB0.x*=cB; OB0.y*=cB; OB0.z*=cB; OB0.w*=cB;
    OB1.x*=cB; OB1.y*=cB; OB1.z*=cB; OB1.w*=cB;
    OB2.x*=cB; OB2.y*=cB; OB2.z*=cB; OB2.w*=cB;
    OB3.x*=cB; OB3.y*=cB; OB3.z*=cB; OB3.w*=cB;
    #pragma unroll
    for (int jj = 0; jj < 8; jj++){
      float pA = __expf(sA[jj] - mnA);
      float pB = __expf(sB[jj] - mnB);
      lA += pA; lB += pB;
      const float4* vv = (const float4*)(myKV + jj*256 + 128 + h*16);
      float4 v0 = vv[0], v1 = vv[1], v2 = vv[2], v3 = vv[3];
      OA0.x = fmaf(pA, v0.x, OA0.x); OA0.y = fmaf(pA, v0.y, OA0.y);
      OA0.z = fmaf(pA, v0.z, OA0.z); OA0.w = fmaf(pA, v0.w, OA0.w);
      OA1.x = fmaf(pA, v1.x, OA1.x); OA1.y = fmaf(pA, v1.y, OA1.y);
      OA1.z = fmaf(pA, v1.z, OA1.z); OA1.w = fmaf(pA, v1.w, OA1.w);
      OA2.x = fmaf(pA, v2.x, OA2.x); OA2.y = fmaf(pA, v2.y, OA2.y);
      OA2.z = fmaf(pA, v2.z, OA2.z); OA2.w = fmaf(pA, v2.w, OA2.w);
      OA3.x = fmaf(pA, v3.x, OA3.x); OA3.y = fmaf(pA, v3.y, OA3.y);
      OA3.z = fmaf(pA, v3.z, OA3.z); OA3.w = fmaf(pA, v3.w, OA3.w);
      OB0.x = fmaf(pB, v0.x, OB0.x); OB0.y = fmaf(pB, v0.y, OB0.y);
      OB0.z = fmaf(pB, v0.z, OB0.z); OB0.w = fmaf(pB, v0.w, OB0.w);
      OB1.x = fmaf(pB, v1.x, OB1.x); OB1.y = fmaf(pB, v1.y, OB1.y);
      OB1.z = fmaf(pB, v1.z, OB1.z); OB1.w = fmaf(pB, v1.w, OB1.w);
      OB2.x = fmaf(pB, v2.x, OB2.x); OB2.y = fmaf(pB, v2.y, OB2.y);
      OB2.z = fmaf(pB, v2.z, OB2.z); OB2.w = fmaf(pB, v2.w, OB2.w);
      OB3.x = fmaf(pB, v3.x, OB3.x); OB3.y = fmaf(pB, v3.y, OB3.y);
      OB3.z = fmaf(pB, v3.z, OB3.z); OB3.w = fmaf(pB, v3.w, OB3.w);
    }
    mA = mnA; mB = mnB;
  }

  __syncthreads();
  if (g > 0){
    float* bA = sKV + (size_t)((g-1)*128 + tt*2)*19;
    bA[0]=mA; bA[1]=lA;
    bA[2]=OA0.x; bA[3]=OA0.y; bA[4]=OA0.z; bA[5]=OA0.w;
    bA[6]=OA1.x; bA[7]=OA1.y; bA[8]=OA1.z; bA[9]=OA1.w;
    bA[10]=OA2.x; bA[11]=OA2.y; bA[12]=OA2.z; bA[13]=OA2.w;
    bA[14]=OA3.x; bA[15]=OA3.y; bA[16]=OA3.z; bA[17]=OA3.w;
    float* bB = bA + 19;
    bB[0]=mB; bB[1]=lB;
    bB[2]=OB0.x; bB[3]=OB0.y; bB[4]=OB0.z; bB[5]=OB0.w;
    bB[6]=OB1.x; bB[7]=OB1.y; bB[8]=OB1.z; bB[9]=OB1.w;
    bB[10]=OB2.x; bB[11]=OB2.y; bB[12]=OB2.z; bB[13]=OB2.w;
    bB[14]=OB3.x; bB[15]=OB3.y; bB[16]=OB3.z; bB[17]=OB3.w;
  }
  __syncthreads();
  if (g == 0){
    float M = mA, L = lA;
    float O[16] = {OA0.x,OA0.y,OA0.z,OA0.w, OA1.x,OA1.y,OA1.z,OA1.w,
                   OA2.x,OA2.y,OA2.z,OA2.w, OA3.x,OA3.y,OA3.z,OA3.w};
    #pragma unroll
    for (int gg = 1; gg < 4; gg++){
      const float* br = sKV + (size_t)((gg-1)*128 + tt*2)*19;
      float m1 = br[0], l1 = br[1];
      float Mn = fmaxf(M, m1);
      float e0 = __expf(M - Mn), e1 = __expf(m1 - Mn);
      L = L*e0 + l1*e1;
      #pragma unroll
      for (int k = 0; k < 16; k++) O[k] = O[k]*e0 + br[2+k]*e1;
      M = Mn;
    }
    int rowA = qt*16 + qp;
    float* dst = isLig ? (partL + ((size_t)(rowA*8 + h)*8 + slice)*18)
                       : (partP + ((size_t)(rowA*8 + h)*4 + slice)*18);
    dst[0] = M; dst[1] = L;
    #pragma unroll
    for (int k = 0; k < 16; k++) dst[2+k] = O[k];
    M = mB; L = lB;
    float Ob[16] = {OB0.x,OB0.y,OB0.z,OB0.w, OB1.x,OB1.y,OB1.z,OB1.w,
                    OB2.x,OB2.y,OB2.z,OB2.w, OB3.x,OB3.y,OB3.z,OB3.w};
    #pragma unroll
    for (int gg = 1; gg < 4; gg++){
      const float* br = sKV + (size_t)((gg-1)*128 + tt*2 + 1)*19;
      float m1 = br[0], l1 = br[1];
      float Mn = fmaxf(M, m1);
      float e0 = __expf(M - Mn), e1 = __expf(m1 - Mn);
      L = L*e0 + l1*e1;
      #pragma unroll
      for (int k = 0; k < 16; k++) Ob[k] = Ob[k]*e0 + br[2+k]*e1;
      M = Mn;
    }
    int rowB = qt*16 + qp + 8;
    float* dstB = isLig ? (partL + ((size_t)(rowB*8 + h)*8 + slice)*18)
                        : (partP + ((size_t)(rowB*8 + h)*4 + slice)*18);
    dstB[0] = M; dstB[1] = L;
    #pragma unroll
    for (int k = 0; k < 16; k++) dstB[2+k] = Ob[k];
  }
}

__global__ __launch_bounds__(256) void merge_ln(const float* __restrict__ partL, const float* __restrict__ partP,
                                                const float* __restrict__ lenh, const float* __restrict__ penh,
                                                const float* __restrict__ WoT, const float* __restrict__ bo,
                                                const float* __restrict__ g_l, const float* __restrict__ be_l,
                                                const float* __restrict__ g_p, const float* __restrict__ be_p,
                                                float* __restrict__ out){
  int b = blockIdx.x, t = threadIdx.x;
  int r0 = b*2;
  int r = t >> 7, c = t & 127;
  int gr = r0 + r;
  int h = c >> 4, cc = c & 15;
  int ns; const float* base;
  if (gr < NL){ ns = 8; base = partL + ((size_t)(gr*8 + h))*8*18; }
  else        { ns = 4; base = partP + ((size_t)((gr-NL)*8 + h))*4*18; }
  float M = -1e30f;
  for (int s = 0; s < ns; s++) M = fmaxf(M, base[s*18]);
  float Lsum = 0.f, Osum = 0.f;
  for (int s = 0; s < ns; s++){
    float e = __expf(base[s*18] - M);
    Lsum = fmaf(e, base[s*18+1], Lsum);
    Osum = fmaf(e, base[s*18+2+cc], Osum);
  }
  __shared__ float sAtt[2*HDIM];
  sAtt[t] = Osum / Lsum;
  __syncthreads();
  float o = bo[c];
  const float* sA = sAtt + r*HDIM;
  #pragma unroll 8
  for (int k = 0; k < 128; k++) o = fmaf(WoT[k*128 + c], sA[k], o);
  const float* enh = (gr < NL) ? (lenh + (size_t)gr*HDIM) : (penh + (size_t)(gr-NL)*HDIM);
  float x = enh[c] + o;
  __shared__ float sred[8];
  int wid = t >> 6;
  float v = x;
  #pragma unroll
  for (int off = 32; off; off >>= 1) v += __shfl_down(v, off);
  if ((t & 63) == 0) sred[wid] = v;
  __syncthreads();
  float mu = (sred[2*r] + sred[2*r+1]) * (1.f/128.f);
  float dx = x - mu;
  v = dx*dx;
  #pragma unroll
  for (int off = 32; off; off >>= 1) v += __shfl_down(v, off);
  if ((t & 63) == 0) sred[4 + wid] = v;
  __syncthreads();
  float var = (sred[4 + 2*r] + sred[4 + 2*r+1]) * (1.f/128.f);
  float y = dx * rsqrtf(var + 1e-5f);
  if (gr < NL) y = fmaf(y, g_l[c], be_l[c]);
  else         y = fmaf(y, g_p[c], be_p[c]);
  out[(size_t)gr*HDIM + c] = y;
}

extern "C" void kernel_launch(void* const* d_in, const int* in_sizes, int n_in,
                              void* d_out, int out_size, void* d_ws, size_t ws_size,
                              hipStream_t stream){
  const float* lf   = (const float*)d_in[0];
  const float* pf   = (const float*)d_in[1];
  const float* lc   = (const float*)d_in[2];
  const float* pc   = (const float*)d_in[3];
  const float* Wl   = (const float*)d_in[4];
  const float* bl   = (const float*)d_in[5];
  const float* Wp   = (const float*)d_in[6];
  const float* bp   = (const float*)d_in[7];
  const float* Wd1  = (const float*)d_in[8];
  const float* bd1  = (const float*)d_in[9];
  const float* Wd2  = (const float*)d_in[10];
  const float* bd2  = (const float*)d_in[11];
  const float* Wd3  = (const float*)d_in[12];
  const float* bd3  = (const float*)d_in[13];
  const float* Wgl  = (const float*)d_in[14];
  const float* bgl  = (const float*)d_in[15];
  const float* Wgp  = (const float*)d_in[16];
  const float* bgp  = (const float*)d_in[17];
  const float* Wqkv = (const float*)d_in[18];
  const float* bqkv = (const float*)d_in[19];
  const float* Wo   = (const float*)d_in[20];
  const float* bo   = (const float*)d_in[21];
  const float* g_l  = (const float*)d_in[22];
  const float* be_l = (const float*)d_in[23];
  const float* g_p  = (const float*)d_in[24];
  const float* be_p = (const float*)d_in[25];

  float* ws  = (float*)d_ws;
  float* out = (float*)d_out;

  // One-time schedulability check (host-side driver query; capture-safe, enqueues nothing).
  // Only attempt the cooperative launch if the fused kernel can run 1 block/CU —
  // a coop launch that fails inside graph capture would poison the capture.
  static int coop_ok = -1;
  if (coop_ok < 0){
    int nb = 0;
    hipError_t qe = hipOccupancyMaxActiveBlocksPerMultiprocessor(&nb, (const void*)fused_all, 512, 0);
    coop_ok = (qe == hipSuccess && nb >= 1) ? 1 : 0;
  }

  if (coop_ok == 1){
    void* args[] = { (void*)&lf, (void*)&pf, (void*)&lc, (void*)&pc,
                     (void*)&Wl, (void*)&bl, (void*)&Wp, (void*)&bp,
                     (void*)&Wd1, (void*)&bd1, (void*)&Wd2, (void*)&bd2,
                     (void*)&Wd3, (void*)&bd3, (void*)&Wgl, (void*)&bgl,
                     (void*)&Wgp, (void*)&bgp, (void*)&Wqkv, (void*)&bqkv,
                     (void*)&Wo, (void*)&bo, (void*)&g_l, (void*)&be_l,
                     (void*)&g_p, (void*)&be_p, (void*)&ws, (void*)&out };
    hipError_t err = hipLaunchCooperativeKernel((const void*)fused_all,
                                                dim3(256), dim3(512), args, 0, stream);
    if (err == hipSuccess) return;
    coop_ok = 0;   // never retry a failing config
  }

  // Fallback: proven 5-kernel pipeline
  float* lig   = ws + LIG_OFF;
  float* poc   = ws + POC_OFF;
  float* lenh  = ws + LENH_OFF;
  float* penh  = ws + PENH_OFF;
  float* qkvl  = ws + QKVL_OFF;
  float* qkvp  = ws + QKVP_OFF;
  float* partL = ws + PARTL_OFF;
  float* partP = ws + PARTP_OFF;
  float* tab   = ws + TAB_OFF;

  prep_all<<<192, 256, 0, stream>>>(Wl, Wp, Wqkv, Wo, Wgl, Wgp, Wd1, bd1, Wd2, bd2, Wd3, bd3, ws);
  proj_kernel<<<NL/2 + NP/2, 256, 0, stream>>>(lf, pf, ws + WLT_OFF, bl, ws + WPT_OFF, bp, lig, poc);
  agg_gate_fused<<<NL/2 + NP/2, 512, 0, stream>>>(lc, pc, tab, lig, poc,
                                                  ws + WGLT_OFF, bgl, ws + WGPT_OFF, bgp,
                                                  ws + WQT_OFF, bqkv,
                                                  lenh, penh, qkvl, qkvp);
  attn_part<<<512, 256, 0, stream>>>(qkvl, qkvp, partL, partP);
  merge_ln<<<NL/2 + NP/2, 256, 0, stream>>>(partL, partP, lenh, penh, ws + WOT_OFF, bo,
                                            g_l, be_l, g_p, be_p, out);
}

// Round 4
// 195.150 us; speedup vs baseline: 2.8998x; 1.0008x over previous
//
#include <hip/hip_runtime.h>
#include <hip/hip_cooperative_groups.h>
#include <math.h>

namespace cg = cooperative_groups;

#define NL 512
#define NP 1024
#define HDIM 128

#define TAB_N 8192
#define DMAX 34.65f

// ---- workspace layout (float offsets) ----
#define M_OFF    128
#define WLT_OFF  (M_OFF)                      // WlT  [128][128]
#define WPT_OFF  (M_OFF + 16384)              // WpT  [128][128]
#define WQT_OFF  (M_OFF + 32768)              // WqkvT[128][384]
#define WOT_OFF  (M_OFF + 81920)              // WoT  [128][128]
#define WGLT_OFF (M_OFF + 98304)              // WglT [256][128]
#define WGPT_OFF (M_OFF + 131072)             // WgpT [256][128]
#define TAB_OFF  (M_OFF + 163840)             // m(d) table
#define LIG_OFF  (M_OFF + NL*NP)              // lig proj 512x128
#define POC_OFF  (LIG_OFF + NL*HDIM)          // poc proj 1024x128
#define LENH_OFF (POC_OFF + NP*HDIM)          // lig_enh 512x128
#define PENH_OFF (LENH_OFF + NL*HDIM)         // poc_enh 1024x128
#define QKVL_OFF (PENH_OFF + NP*HDIM)         // qkv for lig_enh 512x384
#define QKVP_OFF (QKVL_OFF + NL*384)          // qkv for poc_enh 1024x384
#define PARTL_OFF (QKVP_OFF + NP*384)         // lig partials: [512][8 h][8 slices][18]
#define PARTP_OFF (PARTL_OFF + 512*8*8*18)    // poc partials: [1024][8 h][4 slices][18]

__device__ __forceinline__ float dot4f(float4 a, float4 b){
  return fmaf(a.x,b.x, fmaf(a.y,b.y, fmaf(a.z,b.z, a.w*b.w)));
}

// ---- P2a: softmax over partners + aggregation for ONE row, whole block (512 thr).
// PERT = partners/512 (2 for lig rows (n=1024), 1 for poc rows (n=512)).
// Result (128 floats) -> aggDst (LDS). Scratch: smem[0..3081].
template<int PERT>
__device__ __forceinline__ void agg_row(int t, int row,
                                        const float* __restrict__ myC,
                                        const float* __restrict__ otC,
                                        const float* __restrict__ otherFeat,
                                        const float* __restrict__ tab,
                                        float* __restrict__ smem,
                                        float* __restrict__ aggDst)
{
  const int n = PERT * 512;
  float*  w     = smem;                       // n floats (max 1024)
  float4* part4 = (float4*)(smem + 1024);     // 512 float4 = 2048 floats [1024,3072)
  float*  redm  = smem + 3072;                // 10 floats

  int lane = t & 63, wv = t >> 6;
  const float inv_h = (float)(TAB_N - 1) / DMAX;

  float cx = myC[row*3+0], cy = myC[row*3+1], cz = myC[row*3+2];

  float xs[PERT];
  float lmax = -1e30f;
  #pragma unroll
  for (int k = 0; k < PERT; k++){
    int j = t + (k << 9);
    float ox = otC[j*3+0], oy = otC[j*3+1], oz = otC[j*3+2];
    float dx = cx-ox, dy = cy-oy, dz = cz-oz;
    float d = sqrtf(fmaf(dx,dx, fmaf(dy,dy, dz*dz)));
    float xf = d * inv_h;
    int i0 = (int)xf;
    i0 = (i0 > TAB_N-2) ? (TAB_N-2) : i0;
    float f = xf - (float)i0;
    float v0 = tab[i0], v1 = tab[i0+1];
    xs[k] = -fmaf(f, v1 - v0, v0);
    lmax = fmaxf(lmax, xs[k]);
  }
  float v = lmax;
  #pragma unroll
  for (int off = 32; off; off >>= 1) v = fmaxf(v, __shfl_down(v, off));
  if (lane == 0) redm[wv] = v;
  __syncthreads();
  if (t == 0){
    float m = redm[0];
    #pragma unroll
    for (int i = 1; i < 8; i++) m = fmaxf(m, redm[i]);
    redm[8] = m;
  }
  __syncthreads();
  float gm = redm[8];
  float lsum = 0.f;
  #pragma unroll
  for (int k = 0; k < PERT; k++){
    float e = __expf(xs[k] - gm);
    w[t + (k << 9)] = e;
    lsum += e;
  }
  v = lsum;
  #pragma unroll
  for (int off = 32; off; off >>= 1) v += __shfl_down(v, off);
  if (lane == 0) redm[wv] = v;
  __syncthreads();
  if (t == 0){
    float s = 0.f;
    #pragma unroll
    for (int i = 0; i < 8; i++) s += redm[i];
    redm[9] = 1.0f / s;
  }
  __syncthreads();

  // aggregation: 16 j-groups x 32 float4 cols
  {
    int jg = t >> 5;                          // 0..15
    int c4 = t & 31;
    const int per2 = n >> 4;                  // 64 (lig) or 32 (poc)
    int jb0 = jg * per2;
    const float4* of4 = (const float4*)otherFeat;
    float4 acc = {0,0,0,0};
    #pragma unroll 4
    for (int jj = 0; jj < per2; jj++){
      int j = jb0 + jj;
      float4 f = of4[(size_t)j*32 + c4];
      float ww = w[j];
      acc.x = fmaf(ww, f.x, acc.x); acc.y = fmaf(ww, f.y, acc.y);
      acc.z = fmaf(ww, f.z, acc.z); acc.w = fmaf(ww, f.w, acc.w);
    }
    part4[jg*32 + c4] = acc;
  }
  __syncthreads();
  #pragma unroll
  for (int s2 = 8; s2 >= 1; s2 >>= 1){
    if (t < s2*32){
      int g2 = t >> 5, rem = t & 31;
      float4 a = part4[g2*32 + rem], bb = part4[(g2+s2)*32 + rem];
      a.x += bb.x; a.y += bb.y; a.z += bb.z; a.w += bb.w;
      part4[g2*32 + rem] = a;
    }
    __syncthreads();
  }
  float sinv = redm[9];
  if (t < 128) aggDst[t] = ((const float*)part4)[t] * sinv;
  __syncthreads();
}

// =====================================================================================
// Fused cooperative kernel: 512 blocks x 512 threads, 64 KB LDS, 2 blocks/CU
// (16 waves/CU = 50% occupancy vs R3's 25%). __launch_bounds__(512,2) -> VGPR cap 128
// (R3 measured 116 under the same cap -> no spill). Coop launch gated on occupancy>=2.
// Phases: P0 transposes+LUT | P1 proj | P2 agg+gate+QKV (block-local) | P3 attn | P4 merge+LN
// =====================================================================================
__global__ __launch_bounds__(512, 2) void fused_all(
  const float* __restrict__ lf, const float* __restrict__ pf,
  const float* __restrict__ lc, const float* __restrict__ pc,
  const float* __restrict__ Wl, const float* __restrict__ bl,
  const float* __restrict__ Wp, const float* __restrict__ bp,
  const float* __restrict__ Wd1, const float* __restrict__ bd1,
  const float* __restrict__ Wd2, const float* __restrict__ bd2,
  const float* __restrict__ Wd3, const float* __restrict__ bd3,
  const float* __restrict__ Wgl, const float* __restrict__ bgl,
  const float* __restrict__ Wgp, const float* __restrict__ bgp,
  const float* __restrict__ Wqkv, const float* __restrict__ bqkv,
  const float* __restrict__ Wo, const float* __restrict__ bo,
  const float* __restrict__ g_l, const float* __restrict__ be_l,
  const float* __restrict__ g_p, const float* __restrict__ be_p,
  float* __restrict__ ws, float* __restrict__ out)
{
  cg::grid_group grd = cg::this_grid();
  const int b = blockIdx.x;      // 0..511
  const int t = threadIdx.x;     // 0..511

  __shared__ __align__(16) float smem[16384];   // 64 KB

  float* WlT   = ws + WLT_OFF;
  float* WpT   = ws + WPT_OFF;
  float* WqkvT = ws + WQT_OFF;
  float* WoT   = ws + WOT_OFF;
  float* WglT  = ws + WGLT_OFF;
  float* WgpT  = ws + WGPT_OFF;
  float* tab   = ws + TAB_OFF;
  float* lig   = ws + LIG_OFF;
  float* poc   = ws + POC_OFF;
  float* lenh  = ws + LENH_OFF;
  float* penh  = ws + PENH_OFF;
  float* qkvl  = ws + QKVL_OFF;
  float* qkvp  = ws + QKVP_OFF;
  float* partL = ws + PARTL_OFF;
  float* partP = ws + PARTP_OFF;

  // ---------------- P0: weight transposes (blocks 0..319) + m(d) LUT (blocks 496..511) ----------------
  {
    int e = b*512 + t;                   // 0..262143
    if (e < 16384){
      int o = e >> 7, k = e & 127;
      WlT[k*128 + o] = Wl[e];
    } else if (e < 32768){
      int loc = e - 16384, o = loc >> 7, k = loc & 127;
      WpT[k*128 + o] = Wp[loc];
    } else if (e < 81920){                // Wqkv [384][128]
      int loc = e - 32768, o = loc >> 7, k = loc & 127;
      WqkvT[k*384 + o] = Wqkv[loc];
    } else if (e < 98304){                // Wo [128][128]
      int loc = e - 81920, o = loc >> 7, k = loc & 127;
      WoT[k*128 + o] = Wo[loc];
    } else if (e < 131072){               // Wgl [128][256]
      int loc = e - 98304, o = loc >> 8, k = loc & 255;
      WglT[k*128 + o] = Wgl[loc];
    } else if (e < 163840){               // Wgp [128][256]
      int loc = e - 131072, o = loc >> 8, k = loc & 255;
      WgpT[k*128 + o] = Wgp[loc];
    }

    if (b >= 496){
      // LUT: blocks 496..511, 512 entries each (these blocks have no transpose work)
      float* sWd1  = smem;          // 32
      float* sbd1  = smem + 32;     // 32
      float* sbd2  = smem + 64;     // 64
      float* swd3m = smem + 128;    // 64
      float* sWd2  = smem + 256;    // 2048
      if (t < 64){
        float ssum = 0.f;
        #pragma unroll 8
        for (int i = 0; i < 128; i++) ssum += Wd3[i*64 + t];
        swd3m[t] = ssum * (1.f/128.f);
      } else if (t == 64){
        float ssum = 0.f;
        for (int i = 0; i < 128; i++) ssum += bd3[i];
        smem[192] = ssum * (1.f/128.f);
      } else if (t >= 128 && t < 160){ sWd1[t-128] = Wd1[t-128]; sbd1[t-128] = bd1[t-128]; }
      else if (t >= 160 && t < 224){ sbd2[t-160] = bd2[t-160]; }
      for (int k = t; k < 2048; k += 512) sWd2[k] = Wd2[k];
      __syncthreads();

      int idx = (b - 496)*512 + t;
      float d = (float)idx * (DMAX / (float)(TAB_N - 1));
      float4 e1q[8];
      const float4* w1q = (const float4*)sWd1;
      const float4* b1q = (const float4*)sbd1;
      #pragma unroll
      for (int k4 = 0; k4 < 8; k4++){
        float4 w = w1q[k4], bb = b1q[k4];
        float4 ev;
        ev.x = fmaxf(fmaf(d, w.x, bb.x), 0.f);
        ev.y = fmaxf(fmaf(d, w.y, bb.y), 0.f);
        ev.z = fmaxf(fmaf(d, w.z, bb.z), 0.f);
        ev.w = fmaxf(fmaf(d, w.w, bb.w), 0.f);
        e1q[k4] = ev;
      }
      float mv = smem[192];
      #pragma unroll 4
      for (int j2 = 0; j2 < 64; j2++){
        const float4* wrow = (const float4*)(sWd2 + j2*32);
        float a0 = 0.f, a1 = 0.f, a2 = 0.f, a3 = 0.f;
        #pragma unroll
        for (int k4 = 0; k4 < 8; k4++){
          float4 w = wrow[k4], ev = e1q[k4];
          a0 = fmaf(w.x, ev.x, a0);
          a1 = fmaf(w.y, ev.y, a1);
          a2 = fmaf(w.z, ev.z, a2);
          a3 = fmaf(w.w, ev.w, a3);
        }
        float e2v = fmaxf(sbd2[j2] + ((a0+a1)+(a2+a3)), 0.f);
        mv = fmaf(swd3m[j2], e2v, mv);
      }
      tab[idx] = mv;
    }
  }
  grd.sync();

  // ---------------- P1: input projections (768 row-pair tasks over 1024 subgroup slots) ----------------
  {
    int sub = t >> 8, st = t & 255;
    int s = b*2 + sub;                      // 0..1023
    if (s < 768){
      bool isLig = (s < 256);
      int r0 = isLig ? s*2 : (s - 256)*2;
      const float* in  = (isLig ? lf : pf) + (size_t)r0*HDIM;
      const float* WT  = isLig ? WlT : WpT;
      const float* bia = isLig ? bl : bp;
      float* o = (isLig ? lig : poc) + (size_t)r0*HDIM;
      float* sx = smem + sub*256;
      sx[st] = in[st];
      __syncthreads();
      int r = st >> 7, col = st & 127;
      const float* xr = sx + r*HDIM;
      float acc = bia[col];
      #pragma unroll 8
      for (int k = 0; k < 128; k++) acc = fmaf(WT[k*128 + col], xr[k], acc);
      o[r*HDIM + col] = acc;
    }
  }
  grd.sync();

  // ---------------- P2: agg (block-local) + gate + QKV ----------------
  // Block b owns lig row {b} and poc rows {2b, 2b+1}; agg rows stay in LDS.
  {
    float* AGG = smem + 3104;                 // 3 rows x 128 = 384 floats [3104,3488)
    agg_row<2>(t, b,      lc, pc, poc, tab, smem, AGG);        // lig row
    agg_row<1>(t, 2*b,    pc, lc, lig, tab, smem, AGG + 128);  // poc row 0
    agg_row<1>(t, 2*b+1,  pc, lc, lig, tab, smem, AGG + 256);  // poc row 1

    float* sx    = smem + 4096;   // 128
    float* se    = smem + 4224;   // 128
    float* gpart = smem + 4352;   // 512
    for (int i = 0; i < 3; i++){
      bool isLig = (i == 0);
      int row = isLig ? b : (2*b + (i - 1));
      const float* xsrc = (isLig ? lig : poc) + (size_t)row*HDIM;
      const float* arow = AGG + i*128;
      __syncthreads();
      if (t < 128) sx[t] = xsrc[t];
      __syncthreads();
      {
        int col = t & 127, kg = t >> 7;       // kg 0..3: k-quarter of [0,256)
        const float* WT = isLig ? WglT : WgpT;
        const float* inb = (kg < 2) ? sx : (arow - 128);
        int k0 = kg*64;
        float acc = 0.f;
        #pragma unroll 8
        for (int kk = 0; kk < 64; kk++){
          int k = k0 + kk;
          acc = fmaf(WT[(size_t)k*128 + col], inb[k], acc);
        }
        gpart[kg*128 + col] = acc;
      }
      __syncthreads();
      if (t < 128){
        const float* bg = isLig ? bgl : bgp;
        float g = bg[t] + ((gpart[t] + gpart[128+t]) + (gpart[256+t] + gpart[384+t]));
        g = 1.0f / (1.0f + __expf(-g));
        float xv = sx[t], av = arow[t];
        float enh = fmaf(g, xv - av, av);     // g*x + (1-g)*a
        se[t] = enh;
        float* dst = isLig ? (lenh + (size_t)row*HDIM) : (penh + (size_t)row*HDIM);
        dst[t] = enh;
      }
      __syncthreads();
      if (t < 384){
        float acc = bqkv[t];
        #pragma unroll 8
        for (int k = 0; k < 128; k++) acc = fmaf(WqkvT[(size_t)k*384 + t], se[k], acc);
        float* q = (isLig ? qkvl : qkvp) + (size_t)row*384;
        q[t] = acc;
      }
    }
  }
  grd.sync();

  // ---------------- P3: flash attention, exactly 1 task/block, 8 split-k groups x 16 keys ----------------
  // KV LDS chunk swizzle: chunk c -> (c & ~3) | ((c&3) ^ ((c>>2)&3)); cuts 4-way bank conflict to 2-way.
  {
    const float* qsrc; const float* kvsrc; int qt, slice; bool isLig;
    if (b < 256){ isLig = true;  qt = b >> 3; slice = b & 7; qsrc = qkvl; kvsrc = qkvp; }
    else { int b2 = b - 256; isLig = false; qt = b2 >> 2; slice = b2 & 3; qsrc = qkvp; kvsrc = qkvl; }
    int g = t >> 6, tt = t & 63;
    int h = tt >> 3, qp = tt & 7;
    int j0 = slice*128 + g*16;
    int hx = h & 3;

    const float4* qA = (const float4*)(qsrc + (size_t)(qt*16+qp)*384 + h*16);
    const float4* qB = (const float4*)(qsrc + (size_t)(qt*16+qp+8)*384 + h*16);
    float4 a0 = qA[0], a1 = qA[1], a2 = qA[2], a3 = qA[3];
    float4 b0 = qB[0], b1 = qB[1], b2 = qB[2], b3 = qB[3];
    float mA = -1e30f, lA = 0.f, mB = -1e30f, lB = 0.f;
    float4 OA0={0,0,0,0}, OA1={0,0,0,0}, OA2={0,0,0,0}, OA3={0,0,0,0};
    float4 OB0={0,0,0,0}, OB1={0,0,0,0}, OB2={0,0,0,0}, OB3={0,0,0,0};

    float* myKV = smem + g*2048;               // 8 keys x 256 floats per group

    for (int tile = 0; tile < 2; tile++){
      int jbase = j0 + tile*8;
      __syncthreads();
      #pragma unroll
      for (int nn = 0; nn < 8; nn++){
        int v4 = tt + nn*64;
        int jj = v4 >> 6, c4 = v4 & 63;
        int c4s = (c4 & 60) | ((c4 ^ (c4 >> 2)) & 3);
        ((float4*)myKV)[jj*64 + c4s] = *(const float4*)(kvsrc + (size_t)(jbase+jj)*384 + 128 + c4*4);
      }
      __syncthreads();
      float sA[8], sB[8];
      #pragma unroll
      for (int jj = 0; jj < 8; jj++){
        const float4* kb = ((const float4*)myKV) + jj*64 + h*4;
        float4 k0 = kb[0^hx], k1 = kb[1^hx], k2 = kb[2^hx], k3 = kb[3^hx];
        sA[jj] = (dot4f(a0,k0) + dot4f(a1,k1) + dot4f(a2,k2) + dot4f(a3,k3)) * 0.25f;
        sB[jj] = (dot4f(b0,k0) + dot4f(b1,k1) + dot4f(b2,k2) + dot4f(b3,k3)) * 0.25f;
      }
      float mtA = sA[0], mtB = sB[0];
      #pragma unroll
      for (int jj = 1; jj < 8; jj++){ mtA = fmaxf(mtA, sA[jj]); mtB = fmaxf(mtB, sB[jj]); }
      float mnA = fmaxf(mA, mtA), mnB = fmaxf(mB, mtB);
      float cA = __expf(mA - mnA), cB = __expf(mB - mnB);
      lA *= cA; lB *= cB;
      OA0.x*=cA; OA0.y*=cA; OA0.z*=cA; OA0.w*=cA;
      OA1.x*=cA; OA1.y*=cA; OA1.z*=cA; OA1.w*=cA;
      OA2.x*=cA; OA2.y*=cA; OA2.z*=cA; OA2.w*=cA;
      OA3.x*=cA; OA3.y*=cA; OA3.z*=cA; OA3.w*=cA;
      OB0.x*=cB; OB0.y*=cB; OB0.z*=cB; OB0.w*=cB;
      OB1.x*=cB; OB1.y*=cB; OB1.z*=cB; OB1.w*=cB;
      OB2.x*=cB; OB2.y*=cB; OB2.z*=cB; OB2.w*=cB;
      OB3.x*=cB; OB3.y*=cB; OB3.z*=cB; OB3.w*=cB;
      #pragma unroll
      for (int jj = 0; jj < 8; jj++){
        float pA = __expf(sA[jj] - mnA);
        float pB = __expf(sB[jj] - mnB);
        lA += pA; lB += pB;
        const float4* vb = ((const float4*)myKV) + jj*64 + 32 + h*4;
        float4 v0 = vb[0^hx], v1 = vb[1^hx], v2 = vb[2^hx], v3 = vb[3^hx];
        OA0.x = fmaf(pA, v0.x, OA0.x); OA0.y = fmaf(pA, v0.y, OA0.y);
        OA0.z = fmaf(pA, v0.z, OA0.z); OA0.w = fmaf(pA, v0.w, OA0.w);
        OA1.x = fmaf(pA, v1.x, OA1.x); OA1.y = fmaf(pA, v1.y, OA1.y);
        OA1.z = fmaf(pA, v1.z, OA1.z); OA1.w = fmaf(pA, v1.w, OA1.w);
        OA2.x = fmaf(pA, v2.x, OA2.x); OA2.y = fmaf(pA, v2.y, OA2.y);
        OA2.z = fmaf(pA, v2.z, OA2.z); OA2.w = fmaf(pA, v2.w, OA2.w);
        OA3.x = fmaf(pA, v3.x, OA3.x); OA3.y = fmaf(pA, v3.y, OA3.y);
        OA3.z = fmaf(pA, v3.z, OA3.z); OA3.w = fmaf(pA, v3.w, OA3.w);
        OB0.x = fmaf(pB, v0.x, OB0.x); OB0.y = fmaf(pB, v0.y, OB0.y);
        OB0.z = fmaf(pB, v0.z, OB0.z); OB0.w = fmaf(pB, v0.w, OB0.w);
        OB1.x = fmaf(pB, v1.x, OB1.x); OB1.y = fmaf(pB, v1.y, OB1.y);
        OB1.z = fmaf(pB, v1.z, OB1.z); OB1.w = fmaf(pB, v1.w, OB1.w);
        OB2.x = fmaf(pB, v2.x, OB2.x); OB2.y = fmaf(pB, v2.y, OB2.y);
        OB2.z = fmaf(pB, v2.z, OB2.z); OB2.w = fmaf(pB, v2.w, OB2.w);
        OB3.x = fmaf(pB, v3.x, OB3.x); OB3.y = fmaf(pB, v3.y, OB3.y);
        OB3.z = fmaf(pB, v3.z, OB3.z); OB3.w = fmaf(pB, v3.w, OB3.w);
      }
      mA = mnA; mB = mnB;
    }

    // merge 8 split-k groups via LDS (groups 1..7 publish; group 0 merges)
    __syncthreads();
    if (g > 0){
      float* bA = smem + (size_t)((g-1)*128 + tt*2)*18;
      bA[0]=mA; bA[1]=lA;
      bA[2]=OA0.x; bA[3]=OA0.y; bA[4]=OA0.z; bA[5]=OA0.w;
      bA[6]=OA1.x; bA[7]=OA1.y; bA[8]=OA1.z; bA[9]=OA1.w;
      bA[10]=OA2.x; bA[11]=OA2.y; bA[12]=OA2.z; bA[13]=OA2.w;
      bA[14]=OA3.x; bA[15]=OA3.y; bA[16]=OA3.z; bA[17]=OA3.w;
      float* bB = bA + 18;
      bB[0]=mB; bB[1]=lB;
      bB[2]=OB0.x; bB[3]=OB0.y; bB[4]=OB0.z; bB[5]=OB0.w;
      bB[6]=OB1.x; bB[7]=OB1.y; bB[8]=OB1.z; bB[9]=OB1.w;
      bB[10]=OB2.x; bB[11]=OB2.y; bB[12]=OB2.z; bB[13]=OB2.w;
      bB[14]=OB3.x; bB[15]=OB3.y; bB[16]=OB3.z; bB[17]=OB3.w;
    }
    __syncthreads();
    if (g == 0){
      float M = mA, L = lA;
      float O[16] = {OA0.x,OA0.y,OA0.z,OA0.w, OA1.x,OA1.y,OA1.z,OA1.w,
                     OA2.x,OA2.y,OA2.z,OA2.w, OA3.x,OA3.y,OA3.z,OA3.w};
      #pragma unroll
      for (int gg = 1; gg < 8; gg++){
        const float* br = smem + (size_t)((gg-1)*128 + tt*2)*18;
        float m1 = br[0], l1 = br[1];
        float Mn = fmaxf(M, m1);
        float e0 = __expf(M - Mn), e1 = __expf(m1 - Mn);
        L = L*e0 + l1*e1;
        #pragma unroll
        for (int k = 0; k < 16; k++) O[k] = O[k]*e0 + br[2+k]*e1;
        M = Mn;
      }
      int rowA = qt*16 + qp;
      float* dst = isLig ? (partL + ((size_t)(rowA*8 + h)*8 + slice)*18)
                         : (partP + ((size_t)(rowA*8 + h)*4 + slice)*18);
      dst[0] = M; dst[1] = L;
      #pragma unroll
      for (int k = 0; k < 16; k++) dst[2+k] = O[k];
      M = mB; L = lB;
      float Ob[16] = {OB0.x,OB0.y,OB0.z,OB0.w, OB1.x,OB1.y,OB1.z,OB1.w,
                      OB2.x,OB2.y,OB2.z,OB2.w, OB3.x,OB3.y,OB3.z,OB3.w};
      #pragma unroll
      for (int gg = 1; gg < 8; gg++){
        const float* br = smem + (size_t)((gg-1)*128 + tt*2)*18 + 18;
        float m1 = br[0], l1 = br[1];
        float Mn = fmaxf(M, m1);
        float e0 = __expf(M - Mn), e1 = __expf(m1 - Mn);
        L = L*e0 + l1*e1;
        #pragma unroll
        for (int k = 0; k < 16; k++) Ob[k] = Ob[k]*e0 + br[2+k]*e1;
        M = Mn;
      }
      int rowB = qt*16 + qp + 8;
      float* dstB = isLig ? (partL + ((size_t)(rowB*8 + h)*8 + slice)*18)
                          : (partP + ((size_t)(rowB*8 + h)*4 + slice)*18);
      dstB[0] = M; dstB[1] = L;
      #pragma unroll
      for (int k = 0; k < 16; k++) dstB[2+k] = Ob[k];
    }
  }
  grd.sync();

  // ---------------- P4: merge partials + Wo proj + residual + LayerNorm (768 row-pair tasks) ----------------
  {
    int sub = t >> 8, st = t & 255;
    int s = b*2 + sub;                      // 0..1023
    if (s < 768){
      int r0 = s*2;
      int r = st >> 7, c = st & 127;
      int gr = r0 + r;
      int hh = c >> 4, cc = c & 15;
      int ns; const float* base;
      if (gr < NL){ ns = 8; base = partL + ((size_t)(gr*8 + hh))*8*18; }
      else        { ns = 4; base = partP + ((size_t)((gr-NL)*8 + hh))*4*18; }
      float M = -1e30f;
      for (int sl = 0; sl < ns; sl++) M = fmaxf(M, base[sl*18]);
      float Lsum = 0.f, Osum = 0.f;
      for (int sl = 0; sl < ns; sl++){
        float e = __expf(base[sl*18] - M);
        Lsum = fmaf(e, base[sl*18+1], Lsum);
        Osum = fmaf(e, base[sl*18+2+cc], Osum);
      }
      float* sAtt = smem + sub*256;
      float* sred = smem + 512 + sub*16;
      sAtt[st] = Osum / Lsum;
      __syncthreads();
      float o = bo[c];
      const float* sA = sAtt + r*HDIM;
      #pragma unroll 8
      for (int k = 0; k < 128; k++) o = fmaf(WoT[k*128 + c], sA[k], o);
      const float* enh = (gr < NL) ? (lenh + (size_t)gr*HDIM) : (penh + (size_t)(gr-NL)*HDIM);
      float x = enh[c] + o;
      int wid = st >> 6;
      float v = x;
      #pragma unroll
      for (int off = 32; off; off >>= 1) v += __shfl_down(v, off);
      if ((st & 63) == 0) sred[wid] = v;
      __syncthreads();
      float mu = (sred[2*r] + sred[2*r+1]) * (1.f/128.f);
      float dx = x - mu;
      v = dx*dx;
      #pragma unroll
      for (int off = 32; off; off >>= 1) v += __shfl_down(v, off);
      if ((st & 63) == 0) sred[4 + wid] = v;
      __syncthreads();
      float var = (sred[4 + 2*r] + sred[4 + 2*r+1]) * (1.f/128.f);
      float y = dx * rsqrtf(var + 1e-5f);
      if (gr < NL) y = fmaf(y, g_l[c], be_l[c]);
      else         y = fmaf(y, g_p[c], be_p[c]);
      out[(size_t)gr*HDIM + c] = y;
    }
  }
}

// =====================================================================================
// Fallback path: the proven 5-kernel pipeline (used only if coop occupancy check fails)
// =====================================================================================
__device__ __forceinline__ void tpose(const float* __restrict__ src, float* __restrict__ dst,
                                      int O, int K, int blk0, int t){
  int e0 = blk0*1024 + t*4;
  #pragma unroll
  for (int i = 0; i < 4; i++){
    int e = e0 + i;
    int o = e / K, k = e - o*K;
    dst[(size_t)k*O + o] = src[(size_t)o*K + k];
  }
}
__global__ __launch_bounds__(256) void prep_all(const float* __restrict__ Wl, const float* __restrict__ Wp,
                                                const float* __restrict__ Wqkv, const float* __restrict__ Wo,
                                                const float* __restrict__ Wgl, const float* __restrict__ Wgp,
                                                const float* __restrict__ Wd1, const float* __restrict__ bd1,
                                                const float* __restrict__ Wd2, const float* __restrict__ bd2,
                                                const float* __restrict__ Wd3, const float* __restrict__ bd3,
                                                float* __restrict__ ws){
  int b = blockIdx.x, t = threadIdx.x;
  if (b < 160){
    if      (b < 16)  tpose(Wl,   ws + WLT_OFF,  128, 128, b,       t);
    else if (b < 32)  tpose(Wp,   ws + WPT_OFF,  128, 128, b - 16,  t);
    else if (b < 80)  tpose(Wqkv, ws + WQT_OFF,  384, 128, b - 32,  t);
    else if (b < 96)  tpose(Wo,   ws + WOT_OFF,  128, 128, b - 80,  t);
    else if (b < 128) tpose(Wgl,  ws + WGLT_OFF, 128, 256, b - 96,  t);
    else              tpose(Wgp,  ws + WGPT_OFF, 128, 256, b - 128, t);
    return;
  }
  float* tab = ws + TAB_OFF;
  __shared__ float sWd1[32], sbd1[32], sWd2[2048], sbd2[64], swd3m[64];
  __shared__ float sbd3m;
  int idx = (b - 160) * 256 + t;
  if (t < 64){
    float s = 0.f;
    #pragma unroll 8
    for (int i = 0; i < 128; i++) s += Wd3[i*64 + t];
    swd3m[t] = s * (1.f/128.f);
  } else if (t == 64){
    float s = 0.f;
    for (int i = 0; i < 128; i++) s += bd3[i];
    sbd3m = s * (1.f/128.f);
  } else if (t >= 128 && t < 160){ sWd1[t-128] = Wd1[t-128]; sbd1[t-128] = bd1[t-128]; }
  else if (t >= 160 && t < 224){ sbd2[t-160] = bd2[t-160]; }
  for (int k = t; k < 2048; k += 256) sWd2[k] = Wd2[k];
  __syncthreads();

  float d = (float)idx * (DMAX / (float)(TAB_N - 1));
  float4 e1q[8];
  const float4* w1q = (const float4*)sWd1;
  const float4* b1q = (const float4*)sbd1;
  #pragma unroll
  for (int k4 = 0; k4 < 8; k4++){
    float4 w = w1q[k4], bb = b1q[k4];
    float4 e;
    e.x = fmaxf(fmaf(d, w.x, bb.x), 0.f);
    e.y = fmaxf(fmaf(d, w.y, bb.y), 0.f);
    e.z = fmaxf(fmaf(d, w.z, bb.z), 0.f);
    e.w = fmaxf(fmaf(d, w.w, bb.w), 0.f);
    e1q[k4] = e;
  }
  float mv = sbd3m;
  #pragma unroll 4
  for (int j2 = 0; j2 < 64; j2++){
    const float4* wrow = (const float4*)(sWd2 + j2*32);
    float a0 = 0.f, a1 = 0.f, a2 = 0.f, a3 = 0.f;
    #pragma unroll
    for (int k4 = 0; k4 < 8; k4++){
      float4 w = wrow[k4], e = e1q[k4];
      a0 = fmaf(w.x, e.x, a0);
      a1 = fmaf(w.y, e.y, a1);
      a2 = fmaf(w.z, e.z, a2);
      a3 = fmaf(w.w, e.w, a3);
    }
    float e2v = fmaxf(sbd2[j2] + ((a0+a1)+(a2+a3)), 0.f);
    mv = fmaf(swd3m[j2], e2v, mv);
  }
  tab[idx] = mv;
}

__global__ __launch_bounds__(256) void proj_kernel(const float* __restrict__ lf, const float* __restrict__ pf,
                                                   const float* __restrict__ WlT, const float* __restrict__ bl,
                                                   const float* __restrict__ WpT, const float* __restrict__ bp,
                                                   float* __restrict__ lig, float* __restrict__ poc){
  int b = blockIdx.x, t = threadIdx.x;
  bool isLig = (b < NL/2);
  int r0 = isLig ? b*2 : (b - NL/2)*2;
  const float* in = (isLig ? lf : pf) + (size_t)r0*HDIM;
  const float* WT = isLig ? WlT : WpT;
  const float* bias = isLig ? bl : bp;
  float* out = (isLig ? lig : poc) + (size_t)r0*HDIM;
  __shared__ float sx[2*HDIM];
  sx[t] = in[t];
  __syncthreads();
  int r = t >> 7, col = t & 127;
  const float* xr = sx + r*HDIM;
  float acc = bias[col];
  #pragma unroll 8
  for (int k = 0; k < 128; k++) acc = fmaf(WT[k*128 + col], xr[k], acc);
  out[r*HDIM + col] = acc;
}

__global__ __launch_bounds__(512) void agg_gate_fused(const float* __restrict__ lc, const float* __restrict__ pc,
                                                      const float* __restrict__ tab,
                                                      const float* __restrict__ lig, const float* __restrict__ poc,
                                                      const float* __restrict__ WglT, const float* __restrict__ bgl,
                                                      const float* __restrict__ WgpT, const float* __restrict__ bgp,
                                                      const float* __restrict__ WqkvT, const float* __restrict__ bqkv,
                                                      float* __restrict__ lenh, float* __restrict__ penh,
                                                      float* __restrict__ qkvl, float* __restrict__ qkvp){
  int b = blockIdx.x, t = threadIdx.x;
  bool isLig = (b < NL/2);
  int r0 = isLig ? b*2 : (b - NL/2)*2;
  int n = isLig ? NP : NL;
  const float* myFeat = isLig ? lig : poc;
  const float* otherFeat = isLig ? poc : lig;
  const float* myC = isLig ? lc : pc;
  const float* otC = isLig ? pc : lc;

  __shared__ float w[2*NP];
  __shared__ float sx[2*HDIM];
  __shared__ float sa[2*HDIM];
  __shared__ float4 part4[8*64];
  __shared__ float gpart[512];
  __shared__ float redm[8];
  __shared__ float sgm[2], sinv[2];

  int rr = t >> 8, u = t & 255;
  int lane = t & 63, wv = t >> 6;
  int row = r0 + rr;

  if (t < 256) sx[t] = myFeat[(size_t)r0*HDIM + t];

  float cx = myC[row*3+0], cy = myC[row*3+1], cz = myC[row*3+2];
  const float inv_h = (float)(TAB_N - 1) / DMAX;
  int per = n >> 8;

  float xs[4];
  float lmax = -1e30f;
  for (int k = 0; k < per; k++){
    int j = u + (k << 8);
    float ox = otC[j*3+0], oy = otC[j*3+1], oz = otC[j*3+2];
    float dx = cx-ox, dy = cy-oy, dz = cz-oz;
    float d = sqrtf(fmaf(dx,dx, fmaf(dy,dy, dz*dz)));
    float xf = d * inv_h;
    int i0 = (int)xf;
    i0 = (i0 > TAB_N-2) ? (TAB_N-2) : i0;
    float f = xf - (float)i0;
    float v0 = tab[i0], v1 = tab[i0+1];
    xs[k] = -fmaf(f, v1 - v0, v0);
    lmax = fmaxf(lmax, xs[k]);
  }
  float v = lmax;
  #pragma unroll
  for (int off = 32; off; off >>= 1) v = fmaxf(v, __shfl_down(v, off));
  if (lane == 0) redm[wv] = v;
  __syncthreads();
  if (t < 2) sgm[t] = fmaxf(fmaxf(redm[t*4+0], redm[t*4+1]), fmaxf(redm[t*4+2], redm[t*4+3]));
  __syncthreads();
  float gm = sgm[rr];
  float lsum = 0.f;
  for (int k = 0; k < per; k++){
    float e = __expf(xs[k] - gm);
    w[rr*NP + u + (k << 8)] = e;
    lsum += e;
  }
  v = lsum;
  #pragma unroll
  for (int off = 32; off; off >>= 1) v += __shfl_down(v, off);
  if (lane == 0) redm[wv] = v;
  __syncthreads();
  if (t < 2) sinv[t] = 1.0f / ((redm[t*4+0] + redm[t*4+1]) + (redm[t*4+2] + redm[t*4+3]));
  __syncthreads();

  {
    int jg = t >> 6;
    int r  = (t >> 5) & 1;
    int c4 = t & 31;
    int per2 = n >> 3;
    int jb0 = jg * per2;
    const float4* of4 = (const float4*)otherFeat;
    const float* wR = w + r*NP;
    float4 acc = {0,0,0,0};
    #pragma unroll 4
    for (int jj = 0; jj < per2; jj++){
      int j = jb0 + jj;
      float4 f = of4[(size_t)j*32 + c4];
      float ww = wR[j];
      acc.x = fmaf(ww, f.x, acc.x); acc.y = fmaf(ww, f.y, acc.y);
      acc.z = fmaf(ww, f.z, acc.z); acc.w = fmaf(ww, f.w, acc.w);
    }
    part4[(jg*2 + r)*32 + c4] = acc;
  }
  __syncthreads();
  #pragma unroll
  for (int s = 4; s >= 1; s >>= 1){
    if (t < s*64){
      int g2 = t >> 6, rem = t & 63;
      float4 a = part4[g2*64 + rem], bb = part4[(g2+s)*64 + rem];
      a.x += bb.x; a.y += bb.y; a.z += bb.z; a.w += bb.w;
      part4[g2*64 + rem] = a;
    }
    __syncthreads();
  }
  if (t < 256) sa[t] = ((const float*)part4)[t] * sinv[t >> 7];
  __syncthreads();

  {
    int r  = t >> 8;
    int kg = (t >> 7) & 1;
    int col = t & 127;
    const float* WT = isLig ? WglT : WgpT;
    const float* inq = (kg == 0) ? (sx + r*HDIM) : (sa + r*HDIM);
    const float* wbase = WT + (size_t)kg*128*128;
    float g = 0.f;
    #pragma unroll 8
    for (int k = 0; k < 128; k++) g = fmaf(wbase[k*128 + col], inq[k], g);
    gpart[kg*256 + r*128 + col] = g;
  }
  __syncthreads();
  float enh_val = 0.f;
  if (t < 256){
    int r = t >> 7, col = t & 127;
    const float* bg = isLig ? bgl : bgp;
    float g = bg[col] + gpart[t] + gpart[256 + t];
    g = 1.0f / (1.0f + __expf(-g));
    float xv = sx[t], av = sa[t];
    enh_val = fmaf(g, xv - av, av);
    float* dst = isLig ? (lenh + (size_t)(r0+r)*HDIM) : (penh + (size_t)(r0+r)*HDIM);
    dst[col] = enh_val;
  }
  __syncthreads();
  if (t < 256) sa[t] = enh_val;
  __syncthreads();

  {
    int r = t >> 8, ln = t & 255;
    const float* er = sa + r*HDIM;
    float* qout = (isLig ? qkvl : qkvp) + (size_t)(r0+r)*384;
    if (ln < 128){
      float a0 = bqkv[ln], a2 = bqkv[ln+256];
      #pragma unroll 4
      for (int k = 0; k < 128; k++){
        float xv = er[k];
        const float* wk = WqkvT + k*384;
        a0 = fmaf(wk[ln],     xv, a0);
        a2 = fmaf(wk[ln+256], xv, a2);
      }
      qout[ln] = a0; qout[ln+256] = a2;
    } else {
      float a1 = bqkv[ln];
      #pragma unroll 4
      for (int k = 0; k < 128; k++) a1 = fmaf(WqkvT[k*384 + ln], er[k], a1);
      qout[ln] = a1;
    }
  }
}

__global__ __launch_bounds__(256) void attn_part(const float* __restrict__ qkvl, const float* __restrict__ qkvp,
                                                 float* __restrict__ partL, float* __restrict__ partP){
  int bx = blockIdx.x;
  int t = threadIdx.x;
  const float* qsrc; const float* kvsrc; int qt, slice; bool isLig;
  if (bx < 256){ isLig = true;  qt = bx >> 3; slice = bx & 7; qsrc = qkvl; kvsrc = qkvp; }
  else { int b2 = bx - 256; isLig = false; qt = b2 >> 2; slice = b2 & 3; qsrc = qkvp; kvsrc = qkvl; }
  int g = t >> 6, tt = t & 63;
  int h = tt >> 3, qp = tt & 7;
  int j0 = slice*128 + g*32;

  const float4* qA = (const float4*)(qsrc + (size_t)(qt*16+qp)*384 + h*16);
  const float4* qB = (const float4*)(qsrc + (size_t)(qt*16+qp+8)*384 + h*16);
  float4 a0 = qA[0], a1 = qA[1], a2 = qA[2], a3 = qA[3];
  float4 b0 = qB[0], b1 = qB[1], b2 = qB[2], b3 = qB[3];
  float mA = -1e30f, lA = 0.f, mB = -1e30f, lB = 0.f;
  float4 OA0={0,0,0,0}, OA1={0,0,0,0}, OA2={0,0,0,0}, OA3={0,0,0,0};
  float4 OB0={0,0,0,0}, OB1={0,0,0,0}, OB2={0,0,0,0}, OB3={0,0,0,0};

  __shared__ float sKV[8192];
  float* myKV = sKV + g*2048;

  for (int tile = 0; tile < 4; tile++){
    int jbase = j0 + tile*8;
    __syncthreads();
    #pragma unroll
    for (int nn = 0; nn < 8; nn++){
      int v4 = tt + nn*64;
      int jj = v4 >> 6, c4 = v4 & 63;
      ((float4*)myKV)[jj*64 + c4] = *(const float4*)(kvsrc + (size_t)(jbase+jj)*384 + 128 + c4*4);
    }
    __syncthreads();
    float sA[8], sB[8];
    #pragma unroll
    for (int jj = 0; jj < 8; jj++){
      const float4* kk = (const float4*)(myKV + jj*256 + h*16);
      float4 k0 = kk[0], k1 = kk[1], k2 = kk[2], k3 = kk[3];
      sA[jj] = (dot4f(a0,k0) + dot4f(a1,k1) + dot4f(a2,k2) + dot4f(a3,k3)) * 0.25f;
      sB[jj] = (dot4f(b0,k0) + dot4f(b1,k1) + dot4f(b2,k2) + dot4f(b3,k3)) * 0.25f;
    }
    float mtA = sA[0], mtB = sB[0];
    #pragma unroll
    for (int jj = 1; jj < 8; jj++){ mtA = fmaxf(mtA, sA[jj]); mtB = fmaxf(mtB, sB[jj]); }
    float mnA = fmaxf(mA, mtA), mnB = fmaxf(mB, mtB);
    float cA = __expf(mA - mnA), cB = __expf(mB - mnB);
    lA *= cA; lB *= cB;
    OA0.x*=cA; OA0.y*=cA; OA0.z*=cA; OA0.w*=cA;
    OA1.x*=cA; OA1.y*=cA; OA1.z*=cA; OA1.w*=cA;
    OA2.x*=cA; OA2.y*=cA; OA2.z*=cA; OA2.w*=cA;
    OA3.x*=cA; OA3.y*=cA; OA3.z*=cA; OA3.w*=cA;
    OB0.x*=cB; OB0.y*=cB; OB0.z*=cB; OB0.w*=cB;
    OB1.x*=cB; OB1.y*=cB; OB1.z*=cB; OB1.w*=cB;
    OB2.x*=cB; OB2.y*=cB; OB2.z*=cB; OB2.w*=cB;
    OB3.x*=cB; OB3.y*=cB; OB3.z*=cB; OB3.w*=cB;
    #pragma unroll
    for (int jj = 0; jj < 8; jj++){
      float pA = __expf(sA[jj] - mnA);
      float pB = __expf(sB[jj] - mnB);
      lA += pA; lB += pB;
      const float4* vv = (const float4*)(myKV + jj*256 + 128 + h*16);
      float4 v0 = vv[0], v1 = vv[1], v2 = vv[2], v3 = vv[3];
      OA0.x = fmaf(pA, v0.x, OA0.x); OA0.y = fmaf(pA, v0.y, OA0.y);
      OA0.z = fmaf(pA, v0.z, OA0.z); OA0.w = fmaf(pA, v0.w, OA0.w);
      OA1.x = fmaf(pA, v1.x, OA1.x); OA1.y = fmaf(pA, v1.y, OA1.y);
      OA1.z = fmaf(pA, v1.z, OA1.z); OA1.w = fmaf(pA, v1.w, OA1.w);
      OA2.x = fmaf(pA, v2.x, OA2.x); OA2.y = fmaf(pA, v2.y, OA2.y);
      OA2.z = fmaf(pA, v2.z, OA2.z); OA2.w = fmaf(pA, v2.w, OA2.w);
      OA3.x = fmaf(pA, v3.x, OA3.x); OA3.y = fmaf(pA, v3.y, OA3.y);
      OA3.z = fmaf(pA, v3.z, OA3.z); OA3.w = fmaf(pA, v3.w, OA3.w);
      OB0.x = fmaf(pB, v0.x, OB0.x); OB0.y = fmaf(pB, v0.y, OB0.y);
      OB0.z = fmaf(pB, v0.z, OB0.z); OB0.w = fmaf(pB, v0.w, OB0.w);
      OB1.x = fmaf(pB, v1.x, OB1.x); OB1.y = fmaf(pB, v1.y, OB1.y);
      OB1.z = fmaf(pB, v1.z, OB1.z); OB1.w = fmaf(pB, v1.w, OB1.w);
      OB2.x = fmaf(pB, v2.x, OB2.x); OB2.y = fmaf(pB, v2.y, OB2.y);
      OB2.z = fmaf(pB, v2.z, OB2.z); OB2.w = fmaf(pB, v2.w, OB2.w);
      OB3.x = fmaf(pB, v3.x, OB3.x); OB3.y = fmaf(pB, v3.y, OB3.y);
      OB3.z = fmaf(pB, v3.z, OB3.z); OB3.w = fmaf(pB, v3.w, OB3.w);
    }
    mA = mnA; mB = mnB;
  }

  __syncthreads();
  if (g > 0){
    float* bA = sKV + (size_t)((g-1)*128 + tt*2)*19;
    bA[0]=mA; bA[1]=lA;
    bA[2]=OA0.x; bA[3]=OA0.y; bA[4]=OA0.z; bA[5]=OA0.w;
    bA[6]=OA1.x; bA[7]=OA1.y; bA[8]=OA1.z; bA[9]=OA1.w;
    bA[10]=OA2.x; bA[11]=OA2.y; bA[12]=OA2.z; bA[13]=OA2.w;
    bA[14]=OA3.x; bA[15]=OA3.y; bA[16]=OA3.z; bA[17]=OA3.w;
    float* bB = bA + 19;
    bB[0]=mB; bB[1]=lB;
    bB[2]=OB0.x; bB[3]=OB0.y; bB[4]=OB0.z; bB[5]=OB0.w;
    bB[6]=OB1.x; bB[7]=OB1.y; bB[8]=OB1.z; bB[9]=OB1.w;
    bB[10]=OB2.x; bB[11]=OB2.y; bB[12]=OB2.z; bB[13]=OB2.w;
    bB[14]=OB3.x; bB[15]=OB3.y; bB[16]=OB3.z; bB[17]=OB3.w;
  }
  __syncthreads();
  if (g == 0){
    float M = mA, L = lA;
    float O[16] = {OA0.x,OA0.y,OA0.z,OA0.w, OA1.x,OA1.y,OA1.z,OA1.w,
                   OA2.x,OA2.y,OA2.z,OA2.w, OA3.x,OA3.y,OA3.z,OA3.w};
    #pragma unroll
    for (int gg = 1; gg < 4; gg++){
      const float* br = sKV + (size_t)((gg-1)*128 + tt*2)*19;
      float m1 = br[0], l1 = br[1];
      float Mn = fmaxf(M, m1);
      float e0 = __expf(M - Mn), e1 = __expf(m1 - Mn);
      L = L*e0 + l1*e1;
      #pragma unroll
      for (int k = 0; k < 16; k++) O[k] = O[k]*e0 + br[2+k]*e1;
      M = Mn;
    }
    int rowA = qt*16 + qp;
    float* dst = isLig ? (partL + ((size_t)(rowA*8 + h)*8 + slice)*18)
                       : (partP + ((size_t)(rowA*8 + h)*4 + slice)*18);
    dst[0] = M; dst[1] = L;
    #pragma unroll
    for (int k = 0; k < 16; k++) dst[2+k] = O[k];
    M = mB; L = lB;
    float Ob[16] = {OB0.x,OB0.y,OB0.z,OB0.w, OB1.x,OB1.y,OB1.z,OB1.w,
                    OB2.x,OB2.y,OB2.z,OB2.w, OB3.x,OB3.y,OB3.z,OB3.w};
    #pragma unroll
    for (int gg = 1; gg < 4; gg++){
      const float* br = sKV + (size_t)((gg-1)*128 + tt*2 + 1)*19;
      float m1 = br[0], l1 = br[1];
      float Mn = fmaxf(M, m1);
      float e0 = __expf(M - Mn), e1 = __expf(m1 - Mn);
      L = L*e0 + l1*e1;
      #pragma unroll
      for (int k = 0; k < 16; k++) Ob[k] = Ob[k]*e0 + br[2+k]*e1;
      M = Mn;
    }
    int rowB = qt*16 + qp + 8;
    float* dstB = isLig ? (partL + ((size_t)(rowB*8 + h)*8 + slice)*18)
                        : (partP + ((size_t)(rowB*8 + h)*4 + slice)*18);
    dstB[0] = M; dstB[1] = L;
    #pragma unroll
    for (int k = 0; k < 16; k++) dstB[2+k] = Ob[k];
  }
}

__global__ __launch_bounds__(256) void merge_ln(const float* __restrict__ partL, const float* __restrict__ partP,
                                                const float* __restrict__ lenh, const float* __restrict__ penh,
                                                const float* __restrict__ WoT, const float* __restrict__ bo,
                                                const float* __restrict__ g_l, const float* __restrict__ be_l,
                                                const float* __restrict__ g_p, const float* __restrict__ be_p,
                                                float* __restrict__ out){
  int b = blockIdx.x, t = threadIdx.x;
  int r0 = b*2;
  int r = t >> 7, c = t & 127;
  int gr = r0 + r;
  int h = c >> 4, cc = c & 15;
  int ns; const float* base;
  if (gr < NL){ ns = 8; base = partL + ((size_t)(gr*8 + h))*8*18; }
  else        { ns = 4; base = partP + ((size_t)((gr-NL)*8 + h))*4*18; }
  float M = -1e30f;
  for (int s = 0; s < ns; s++) M = fmaxf(M, base[s*18]);
  float Lsum = 0.f, Osum = 0.f;
  for (int s = 0; s < ns; s++){
    float e = __expf(base[s*18] - M);
    Lsum = fmaf(e, base[s*18+1], Lsum);
    Osum = fmaf(e, base[s*18+2+cc], Osum);
  }
  __shared__ float sAtt[2*HDIM];
  sAtt[t] = Osum / Lsum;
  __syncthreads();
  float o = bo[c];
  const float* sA = sAtt + r*HDIM;
  #pragma unroll 8
  for (int k = 0; k < 128; k++) o = fmaf(WoT[k*128 + c], sA[k], o);
  const float* enh = (gr < NL) ? (lenh + (size_t)gr*HDIM) : (penh + (size_t)(gr-NL)*HDIM);
  float x = enh[c] + o;
  __shared__ float sred[8];
  int wid = t >> 6;
  float v = x;
  #pragma unroll
  for (int off = 32; off; off >>= 1) v += __shfl_down(v, off);
  if ((t & 63) == 0) sred[wid] = v;
  __syncthreads();
  float mu = (sred[2*r] + sred[2*r+1]) * (1.f/128.f);
  float dx = x - mu;
  v = dx*dx;
  #pragma unroll
  for (int off = 32; off; off >>= 1) v += __shfl_down(v, off);
  if ((t & 63) == 0) sred[4 + wid] = v;
  __syncthreads();
  float var = (sred[4 + 2*r] + sred[4 + 2*r+1]) * (1.f/128.f);
  float y = dx * rsqrtf(var + 1e-5f);
  if (gr < NL) y = fmaf(y, g_l[c], be_l[c]);
  else         y = fmaf(y, g_p[c], be_p[c]);
  out[(size_t)gr*HDIM + c] = y;
}

extern "C" void kernel_launch(void* const* d_in, const int* in_sizes, int n_in,
                              void* d_out, int out_size, void* d_ws, size_t ws_size,
                              hipStream_t stream){
  const float* lf   = (const float*)d_in[0];
  const float* pf   = (const float*)d_in[1];
  const float* lc   = (const float*)d_in[2];
  const float* pc   = (const float*)d_in[3];
  const float* Wl   = (const float*)d_in[4];
  const float* bl   = (const float*)d_in[5];
  const float* Wp   = (const float*)d_in[6];
  const float* bp   = (const float*)d_in[7];
  const float* Wd1  = (const float*)d_in[8];
  const float* bd1  = (const float*)d_in[9];
  const float* Wd2  = (const float*)d_in[10];
  const float* bd2  = (const float*)d_in[11];
  const float* Wd3  = (const float*)d_in[12];
  const float* bd3  = (const float*)d_in[13];
  const float* Wgl  = (const float*)d_in[14];
  const float* bgl  = (const float*)d_in[15];
  const float* Wgp  = (const float*)d_in[16];
  const float* bgp  = (const float*)d_in[17];
  const float* Wqkv = (const float*)d_in[18];
  const float* bqkv = (const float*)d_in[19];
  const float* Wo   = (const float*)d_in[20];
  const float* bo   = (const float*)d_in[21];
  const float* g_l  = (const float*)d_in[22];
  const float* be_l = (const float*)d_in[23];
  const float* g_p  = (const float*)d_in[24];
  const float* be_p = (const float*)d_in[25];

  float* ws  = (float*)d_ws;
  float* out = (float*)d_out;

  // One-time schedulability check (host-side driver query; capture-safe, enqueues nothing).
  // 512-block coop grid needs >= 2 blocks/CU; never attempt a launch that could fail in capture.
  static int coop_ok = -1;
  if (coop_ok < 0){
    int nb = 0;
    hipError_t qe = hipOccupancyMaxActiveBlocksPerMultiprocessor(&nb, (const void*)fused_all, 512, 0);
    coop_ok = (qe == hipSuccess && nb >= 2) ? 1 : 0;
  }

  if (coop_ok == 1){
    void* args[] = { (void*)&lf, (void*)&pf, (void*)&lc, (void*)&pc,
                     (void*)&Wl, (void*)&bl, (void*)&Wp, (void*)&bp,
                     (void*)&Wd1, (void*)&bd1, (void*)&Wd2, (void*)&bd2,
                     (void*)&Wd3, (void*)&bd3, (void*)&Wgl, (void*)&bgl,
                     (void*)&Wgp, (void*)&bgp, (void*)&Wqkv, (void*)&bqkv,
                     (void*)&Wo, (void*)&bo, (void*)&g_l, (void*)&be_l,
                     (void*)&g_p, (void*)&be_p, (void*)&ws, (void*)&out };
    hipError_t err = hipLaunchCooperativeKernel((const void*)fused_all,
                                                dim3(512), dim3(512), args, 0, stream);
    if (err == hipSuccess) return;
    coop_ok = 0;   // never retry a failing config
  }

  // Fallback: proven 5-kernel pipeline
  float* lig   = ws + LIG_OFF;
  float* poc   = ws + POC_OFF;
  float* lenh  = ws + LENH_OFF;
  float* penh  = ws + PENH_OFF;
  float* qkvl  = ws + QKVL_OFF;
  float* qkvp  = ws + QKVP_OFF;
  float* partL = ws + PARTL_OFF;
  float* partP = ws + PARTP_OFF;
  float* tab   = ws + TAB_OFF;

  prep_all<<<192, 256, 0, stream>>>(Wl, Wp, Wqkv, Wo, Wgl, Wgp, Wd1, bd1, Wd2, bd2, Wd3, bd3, ws);
  proj_kernel<<<NL/2 + NP/2, 256, 0, stream>>>(lf, pf, ws + WLT_OFF, bl, ws + WPT_OFF, bp, lig, poc);
  agg_gate_fused<<<NL/2 + NP/2, 512, 0, stream>>>(lc, pc, tab, lig, poc,
                                                  ws + WGLT_OFF, bgl, ws + WGPT_OFF, bgp,
                                                  ws + WQT_OFF, bqkv,
                                                  lenh, penh, qkvl, qkvp);
  attn_part<<<512, 256, 0, stream>>>(qkvl, qkvp, partL, partP);
  merge_ln<<<NL/2 + NP/2, 256, 0, stream>>>(partL, partP, lenh, penh, ws + WOT_OFF, bo,
                                            g_l, be_l, g_p, be_p, out);
}